// Round 6
// baseline (784.235 us; speedup 1.0000x reference)
//
#include <hip/hip_runtime.h>
#include <stdint.h>

typedef unsigned short u16;
using bf16x8 = __attribute__((ext_vector_type(8))) __bf16;
using f32x4  = __attribute__((ext_vector_type(4))) float;

// ---------- helpers ----------
__device__ __forceinline__ u16 f2bf(float f) {
    uint32_t u = __float_as_uint(f);
    u += 0x7fffu + ((u >> 16) & 1u);          // round-to-nearest-even
    return (u16)(u >> 16);
}
__device__ __forceinline__ float bf2f(u16 u) {
    return __uint_as_float(((uint32_t)u) << 16);
}
__device__ __forceinline__ void gload16(const void* g, void* l) {
    // async global->LDS, 16B per lane; LDS dest = wave-uniform base + lane*16
    __builtin_amdgcn_global_load_lds(
        (__attribute__((address_space(1))) void*)(uintptr_t)g,
        (__attribute__((address_space(3))) void*)(uintptr_t)l,
        16, 0, 0);
}

// ---------- LayerNorm: fp32 in -> bf16 (mode 0) or fp32 (mode 1) out ----------
template <int OUTF32>
__global__ __launch_bounds__(256) void ln_kernel(const float* __restrict__ in,
                                                 const float* __restrict__ g,
                                                 const float* __restrict__ b,
                                                 void* __restrict__ out, int D) {
    const int row = blockIdx.x;
    const int tid = threadIdx.x;
    const float* x = in + (size_t)row * D;
    const int nv = D >> 8;                    // 4 for D=1024, 1 for D=256
    float v[4];
    float s1 = 0.f, s2 = 0.f;
    for (int i = 0; i < nv; ++i) {
        float t = x[tid + (i << 8)];
        v[i] = t; s1 += t; s2 += t * t;
    }
    for (int o = 1; o < 64; o <<= 1) {
        s1 += __shfl_xor(s1, o, 64);
        s2 += __shfl_xor(s2, o, 64);
    }
    __shared__ float r1[4], r2[4];
    const int w = tid >> 6;
    if ((tid & 63) == 0) { r1[w] = s1; r2[w] = s2; }
    __syncthreads();
    s1 = r1[0] + r1[1] + r1[2] + r1[3];
    s2 = r2[0] + r2[1] + r2[2] + r2[3];
    const float mean = s1 / (float)D;
    const float var  = s2 / (float)D - mean * mean;
    const float inv  = rsqrtf(var + 1e-5f);
    for (int i = 0; i < nv; ++i) {
        int c = tid + (i << 8);
        float y = (v[i] - mean) * inv * g[c] + b[c];
        if (OUTF32) ((float*)out)[(size_t)row * D + c] = y;
        else        ((u16*)out)[(size_t)row * D + c] = f2bf(y);
    }
}

// ---------- weight transpose + fp32->bf16 convert ----------
template <int GLUPERM>
__global__ __launch_bounds__(256) void wconvert_t(const float* __restrict__ W,
                                                  u16* __restrict__ Wt,
                                                  int K, int N, int ldw) {
    __shared__ float tile[32][33];
    const int k0 = blockIdx.x * 32, n0 = blockIdx.y * 32;
    const int tx = threadIdx.x & 31, ty = threadIdx.x >> 5;  // 32 x 8
    const int csrc = GLUPERM ? ((tx & 1) * 1024 + (n0 >> 1) + (tx >> 1)) : (n0 + tx);
    for (int i = 0; i < 4; ++i)
        tile[ty + i * 8][tx] = W[(size_t)(k0 + ty + i * 8) * ldw + csrc];
    __syncthreads();
    for (int i = 0; i < 4; ++i)
        Wt[(size_t)(n0 + ty + i * 8) * K + k0 + tx] = f2bf(tile[tx][ty + i * 8]);
}

// ============ GEMM 8-phase: BM=256, BN=256(WM=2)/128(WM=4), BK=64 ============
// C[M,N] = A[M,K](bf16) * Bt[N,K](bf16)^T. 8 waves / 512 thr. K-tile staged as
// two kslot-halves; LDS half = [lines of 2 rows][8 x 16B slots, XOR(line&7)].
// Per tile: 4 (WM=2) or 2 (WM=4) phases, each {ds_reads | 1 half-stage ->
// s_barrier -> lgkmcnt(0) -> setprio(1) 16 MFMA setprio(0) -> counted vmcnt ->
// s_barrier}. Stages target only slots whose reads completed >=1 barrier ago.
// EPI: 0 bf16 ; 1 silu bf16 (+bias) ; 3 f32 res + rscale*(acc+bias) ; 4 GLU
template <int EPI, int WM>
__global__ __launch_bounds__(512, 2) void gemm8p(const u16* __restrict__ A,
                                                 const u16* __restrict__ Bt,
                                                 const float* __restrict__ bias,
                                                 const float* __restrict__ res,
                                                 float rscale,
                                                 void* __restrict__ outp,
                                                 int M, int N, int K, int nbx) {
    constexpr int WN = 8 / WM;                 // 4 or 2
    constexpr int BN = (WM == 2) ? 256 : 128;
    constexpr int FM = (WM == 2) ? 8 : 4;      // m-frags per wave
    constexpr int LB = BN / 128;               // gloads per B-half per wave (2 or 1)
    __shared__ u16 sA[2][2][128 * 64];         // [buf][khalf][line*64]
    __shared__ u16 sB[2][2][(BN / 2) * 64];

    const int tid = threadIdx.x, lane = tid & 63, w = tid >> 6;
    const int wm = w / WN, wn = w % WN;
    const int fr = lane & 15, fq = lane >> 4;
    const int cpx = gridDim.x >> 3;            // bijective XCD swizzle (grid%8==0)
    const int lid = (blockIdx.x & 7) * cpx + (blockIdx.x >> 3);
    const int bn0 = (lid % nbx) * BN;
    const int bm0 = (lid / nbx) * 256;

    // per-thread swizzled read offset within a half (elems) -- compile-folds
    const int rdbase = (fr >> 1) * 64 + ((((((fr & 1) << 2) | fq)) ^ (fr >> 1)) << 3);
    // per-lane stage source constants (inverse swizzle on global src)
    const int s_l = (lane & 7) ^ (lane >> 3);
    const int rowoff_l = 2 * (lane >> 3) + (s_l >> 2);
    const int koff_l = (s_l & 3) << 3;

    f32x4 acc[FM][4] = {};
    const int NK = K >> 6;
    const int arow = wm * (256 / WM);
    const int brow = wn * 64;

#define STAGE_A(bufi, kh, t)                                                    \
    {                                                                           \
        _Pragma("unroll")                                                       \
        for (int c = 0; c < 2; ++c)                                             \
            gload16(A + (size_t)(bm0 + (c * 8 + w) * 16 + rowoff_l) * K         \
                        + ((t) << 6) + (kh) * 32 + koff_l,                      \
                    &sA[bufi][kh][(c * 8 + w) * 512]);                          \
    }
#define STAGE_B(bufi, kh, t)                                                    \
    {                                                                           \
        _Pragma("unroll")                                                       \
        for (int c = 0; c < LB; ++c)                                            \
            gload16(Bt + (size_t)(bn0 + (c * 8 + w) * 16 + rowoff_l) * K        \
                        + ((t) << 6) + (kh) * 32 + koff_l,                      \
                    &sB[bufi][kh][(c * 8 + w) * 512]);                          \
    }
#define RD_A(dst, bufi, kh, r0)                                                 \
    dst = *(const bf16x8*)(&sA[bufi][kh][((r0) >> 1) * 64 + rdbase]);
#define RD_B(dst, bufi, kh, r0)                                                 \
    dst = *(const bf16x8*)(&sB[bufi][kh][((r0) >> 1) * 64 + rdbase]);
#define BARRIER() __builtin_amdgcn_s_barrier()
#define LGK0()                                                                  \
    asm volatile("s_waitcnt lgkmcnt(0)" ::: "memory");                          \
    __builtin_amdgcn_sched_barrier(0)
#define SB() __builtin_amdgcn_sched_barrier(0)

    // ---- prologue: k0(0),k1(0),k0(1) staged; wait only for k0(0) ----
    STAGE_A(0, 0, 0) STAGE_B(0, 0, 0)
    STAGE_A(0, 1, 0) STAGE_B(0, 1, 0)
    STAGE_A(1, 0, 1) STAGE_B(1, 0, 1)
    if constexpr (WM == 2) { asm volatile("s_waitcnt vmcnt(8)" ::: "memory"); }
    else                   { asm volatile("s_waitcnt vmcnt(6)" ::: "memory"); }
    SB();
    BARRIER();

    for (int s = 0; s < NK; ++s) {
        const int buf = s & 1;
        bf16x8 afr[4], bfr[4];
        if constexpr (WM == 2) {
            // ---- ph1: kslot0 x mh0 ; stage A-k1(s+1) ----
#pragma unroll
            for (int i = 0; i < 4; ++i) { RD_B(bfr[i], buf, 0, brow + i * 16) }
#pragma unroll
            for (int i = 0; i < 4; ++i) { RD_A(afr[i], buf, 0, arow + i * 16) }
            if (s + 1 < NK) STAGE_A(buf ^ 1, 1, s + 1)
            BARRIER(); LGK0();
            __builtin_amdgcn_s_setprio(1);
#pragma unroll
            for (int i = 0; i < 4; ++i)
#pragma unroll
                for (int j = 0; j < 4; ++j)
                    acc[i][j] = __builtin_amdgcn_mfma_f32_16x16x32_bf16(
                        bfr[j], afr[i], acc[i][j], 0, 0, 0);    // D[n][m]
            __builtin_amdgcn_s_setprio(0);
            BARRIER();
            // ---- ph2: kslot0 x mh1 ; stage B-k1(s+1) ----
#pragma unroll
            for (int i = 0; i < 4; ++i) { RD_A(afr[i], buf, 0, arow + 64 + i * 16) }
            if (s + 1 < NK) STAGE_B(buf ^ 1, 1, s + 1)
            BARRIER(); LGK0();
            __builtin_amdgcn_s_setprio(1);
#pragma unroll
            for (int i = 0; i < 4; ++i)
#pragma unroll
                for (int j = 0; j < 4; ++j)
                    acc[4 + i][j] = __builtin_amdgcn_mfma_f32_16x16x32_bf16(
                        bfr[j], afr[i], acc[4 + i][j], 0, 0, 0);
            __builtin_amdgcn_s_setprio(0);
            if (s + 1 < NK) { asm volatile("s_waitcnt vmcnt(8)" ::: "memory"); }
            else            { asm volatile("s_waitcnt vmcnt(0)" ::: "memory"); }
            SB();
            BARRIER();
            // ---- ph3: kslot1 x mh0 ; stage A-k0(s+2) ----
#pragma unroll
            for (int i = 0; i < 4; ++i) { RD_B(bfr[i], buf, 1, brow + i * 16) }
#pragma unroll
            for (int i = 0; i < 4; ++i) { RD_A(afr[i], buf, 1, arow + i * 16) }
            if (s + 2 < NK) STAGE_A(buf, 0, s + 2)
            BARRIER(); LGK0();
            __builtin_amdgcn_s_setprio(1);
#pragma unroll
            for (int i = 0; i < 4; ++i)
#pragma unroll
                for (int j = 0; j < 4; ++j)
                    acc[i][j] = __builtin_amdgcn_mfma_f32_16x16x32_bf16(
                        bfr[j], afr[i], acc[i][j], 0, 0, 0);
            __builtin_amdgcn_s_setprio(0);
            BARRIER();
            // ---- ph4: kslot1 x mh1 ; stage B-k0(s+2) ----
#pragma unroll
            for (int i = 0; i < 4; ++i) { RD_A(afr[i], buf, 1, arow + 64 + i * 16) }
            if (s + 2 < NK) STAGE_B(buf, 0, s + 2)
            BARRIER(); LGK0();
            __builtin_amdgcn_s_setprio(1);
#pragma unroll
            for (int i = 0; i < 4; ++i)
#pragma unroll
                for (int j = 0; j < 4; ++j)
                    acc[4 + i][j] = __builtin_amdgcn_mfma_f32_16x16x32_bf16(
                        bfr[j], afr[i], acc[4 + i][j], 0, 0, 0);
            __builtin_amdgcn_s_setprio(0);
            if (s + 1 < NK) {
                if (s + 2 < NK) { asm volatile("s_waitcnt vmcnt(8)" ::: "memory"); }
                else            { asm volatile("s_waitcnt vmcnt(4)" ::: "memory"); }
                SB();
            }
            BARRIER();
        } else {
            // ---- ph1: kslot0 ; stage A,B-k1(s+1) ----
#pragma unroll
            for (int i = 0; i < 4; ++i) { RD_B(bfr[i], buf, 0, brow + i * 16) }
#pragma unroll
            for (int i = 0; i < 4; ++i) { RD_A(afr[i], buf, 0, arow + i * 16) }
            if (s + 1 < NK) { STAGE_A(buf ^ 1, 1, s + 1) STAGE_B(buf ^ 1, 1, s + 1) }
            BARRIER(); LGK0();
            __builtin_amdgcn_s_setprio(1);
#pragma unroll
            for (int i = 0; i < 4; ++i)
#pragma unroll
                for (int j = 0; j < 4; ++j)
                    acc[i][j] = __builtin_amdgcn_mfma_f32_16x16x32_bf16(
                        bfr[j], afr[i], acc[i][j], 0, 0, 0);
            __builtin_amdgcn_s_setprio(0);
            if (s + 1 < NK) { asm volatile("s_waitcnt vmcnt(6)" ::: "memory"); }
            else            { asm volatile("s_waitcnt vmcnt(0)" ::: "memory"); }
            SB();
            BARRIER();
            // ---- ph2: kslot1 ; stage A,B-k0(s+2) ----
#pragma unroll
            for (int i = 0; i < 4; ++i) { RD_B(bfr[i], buf, 1, brow + i * 16) }
#pragma unroll
            for (int i = 0; i < 4; ++i) { RD_A(afr[i], buf, 1, arow + i * 16) }
            if (s + 2 < NK) { STAGE_A(buf, 0, s + 2) STAGE_B(buf, 0, s + 2) }
            BARRIER(); LGK0();
            __builtin_amdgcn_s_setprio(1);
#pragma unroll
            for (int i = 0; i < 4; ++i)
#pragma unroll
                for (int j = 0; j < 4; ++j)
                    acc[i][j] = __builtin_amdgcn_mfma_f32_16x16x32_bf16(
                        bfr[j], afr[i], acc[i][j], 0, 0, 0);
            __builtin_amdgcn_s_setprio(0);
            if (s + 1 < NK) {
                if (s + 2 < NK) { asm volatile("s_waitcnt vmcnt(6)" ::: "memory"); }
                else            { asm volatile("s_waitcnt vmcnt(3)" ::: "memory"); }
                SB();
            }
            BARRIER();
        }
    }

    // epilogue: lane holds rows m = ...+fr, cols n0..n0+3 (n0 = ...+fq*4)
#pragma unroll
    for (int mi = 0; mi < FM; ++mi) {
        const int m = bm0 + wm * (256 / WM) + mi * 16 + fr;
#pragma unroll
        for (int ni = 0; ni < 4; ++ni) {
            const int n0 = bn0 + wn * 64 + ni * 16 + fq * 4;
            if (EPI == 0 || EPI == 1) {
                union { uint2 u2; u16 hh[4]; } ok;
#pragma unroll
                for (int r = 0; r < 4; ++r) {
                    float v = acc[mi][ni][r] + (bias ? bias[n0 + r] : 0.f);
                    if (EPI == 1) v = v / (1.f + __expf(-v));
                    ok.hh[r] = f2bf(v);
                }
                *(uint2*)((u16*)outp + (size_t)m * N + n0) = ok.u2;
            } else if (EPI == 3) {
                const f32x4 rv = *(const f32x4*)(res + (size_t)m * N + n0);
                f32x4 v;
#pragma unroll
                for (int r = 0; r < 4; ++r)
                    v[r] = rv[r] + rscale * (acc[mi][ni][r] + (bias ? bias[n0 + r] : 0.f));
                *(f32x4*)((float*)outp + (size_t)m * N + n0) = v;
            } else {                           // EPI 4: GLU pairs (interleaved cols)
                float vv[4];
#pragma unroll
                for (int r = 0; r < 4; ++r) {
                    const int n = n0 + r;
                    vv[r] = acc[mi][ni][r] + bias[((n & 1) << 10) + (n >> 1)];
                }
                union { uint32_t u; u16 hh[2]; } ok;
                ok.hh[0] = f2bf(vv[0] / (1.f + __expf(-vv[1])));
                ok.hh[1] = f2bf(vv[2] / (1.f + __expf(-vv[3])));
                *(uint32_t*)((u16*)outp + (size_t)m * (N >> 1) + (n0 >> 1)) = ok.u;
            }
        }
    }
#undef STAGE_A
#undef STAGE_B
#undef RD_A
#undef RD_B
#undef BARRIER
#undef LGK0
#undef SB
}

// ---------- GEMM v2 (128x128, for small N / small K shapes) ----------
template <int EPI>
__global__ __launch_bounds__(256) void gemm_bf16(const u16* __restrict__ A,
                                                 const u16* __restrict__ Bt,
                                                 const float* __restrict__ bias,
                                                 const float* __restrict__ res,
                                                 float rscale,
                                                 void* __restrict__ outp,
                                                 int M, int N, int K, int nbx) {
    __shared__ u16 sA[128 * 64];
    __shared__ u16 sB[128 * 64];
    const int tid = threadIdx.x;
    const int lane = tid & 63;
    const int w = tid >> 6;
    const int wm = w >> 1, wn = w & 1;        // 2x2 wave grid
    const int fr = lane & 15, fq = lane >> 4, frx = fr & 7;
    const int cpx = gridDim.x >> 3;
    const int lid = (blockIdx.x & 7) * cpx + (blockIdx.x >> 3);
    const int bn0 = (lid % nbx) * 128;
    const int bm0 = (lid / nbx) * 128;

    f32x4 acc[4][4] = {};

    const int lrow = lane >> 3;
    const int lslot = (lane & 7) ^ lrow;
    const u16* ga0 = A  + (size_t)(bm0 + w * 8 + lrow) * K + lslot * 8;
    const u16* gb0 = Bt + (size_t)(bn0 + w * 8 + lrow) * K + lslot * 8;
    u16* la0 = sA + w * 512;
    u16* lb0 = sB + w * 512;
    const size_t rstep32 = (size_t)32 * K;

    for (int kt = 0; kt < K; kt += 64) {
        __syncthreads();
#pragma unroll
        for (int i = 0; i < 4; ++i) {
            gload16(ga0 + kt + i * rstep32, la0 + i * 2048);
            gload16(gb0 + kt + i * rstep32, lb0 + i * 2048);
        }
        __syncthreads();
#pragma unroll
        for (int kk = 0; kk < 2; ++kk) {
            bf16x8 afr[4], bfr[4];
            const int sl = (((kk * 4 + fq) ^ frx) << 3);
#pragma unroll
            for (int i = 0; i < 4; ++i) {
                afr[i] = *(const bf16x8*)(sA + (wm * 64 + i * 16 + fr) * 64 + sl);
                bfr[i] = *(const bf16x8*)(sB + (wn * 64 + i * 16 + fr) * 64 + sl);
            }
#pragma unroll
            for (int mi = 0; mi < 4; ++mi)
#pragma unroll
                for (int ni = 0; ni < 4; ++ni)
                    acc[mi][ni] = __builtin_amdgcn_mfma_f32_16x16x32_bf16(
                        bfr[ni], afr[mi], acc[mi][ni], 0, 0, 0);
        }
    }

#pragma unroll
    for (int mi = 0; mi < 4; ++mi) {
        const int m = bm0 + wm * 64 + mi * 16 + fr;
#pragma unroll
        for (int ni = 0; ni < 4; ++ni) {
            const int n0 = bn0 + wn * 64 + ni * 16 + fq * 4;
            if (EPI == 0) {
                union { uint2 u2; u16 hh[4]; } ok;
#pragma unroll
                for (int r = 0; r < 4; ++r)
                    ok.hh[r] = f2bf(acc[mi][ni][r] + (bias ? bias[n0 + r] : 0.f));
                *(uint2*)((u16*)outp + (size_t)m * N + n0) = ok.u2;
            } else {
                f32x4 v;
#pragma unroll
                for (int r = 0; r < 4; ++r)
                    v[r] = acc[mi][ni][r] + (bias ? bias[n0 + r] : 0.f);
                *(f32x4*)((float*)outp + (size_t)m * N + n0) = v;
            }
        }
    }
}

// ---------- RoPE tables ----------
__global__ __launch_bounds__(256) void rope_tables_kernel(float* __restrict__ ct,
                                                          float* __restrict__ st) {
    const int i = blockIdx.x * 256 + threadIdx.x;   // 32768
    const int t = i >> 5, j = i & 31;
    const float inv = powf(10000.f, -(float)j / 32.f);
    const float f = (float)t * inv;
    ct[i] = cosf(f);
    st[i] = sinf(f);
}

// ---------- RoPE apply ----------
__global__ __launch_bounds__(256) void rope_kernel(u16* __restrict__ buf,
                                                   const float* __restrict__ ct,
                                                   const float* __restrict__ st,
                                                   int hmask, int hshift, int rstride,
                                                   float scale) {
    const int i = blockIdx.x * 256 + threadIdx.x;
    const int j = i & 31;
    const int hh = (i >> 5) & hmask;
    const int m = i >> (5 + hshift);
    const int t = m & 1023;
    u16* p = buf + (size_t)m * rstride + hh * 64 + j;
    const float c = ct[t * 32 + j], s = st[t * 32 + j];
    const float x1 = bf2f(p[0]), x2 = bf2f(p[32]);
    p[0]  = f2bf((x1 * c - x2 * s) * scale);
    p[32] = f2bf((x2 * c + x1 * s) * scale);
}

// ---------- V transpose ----------
__global__ __launch_bounds__(256) void vtranspose_kernel(const u16* __restrict__ KV,
                                                         u16* __restrict__ Vt) {
    __shared__ u16 tile[32][33];
    const int t0 = blockIdx.x * 32, h0 = blockIdx.y * 32;
    const int bk = blockIdx.z;                 // b*4 + kh
    const int b = bk >> 2, kh = bk & 3;
    const int tx = threadIdx.x & 31, ty = threadIdx.x >> 5;
    for (int i = 0; i < 4; ++i)
        tile[ty + i * 8][tx] =
            KV[(size_t)(b * 1024 + t0 + ty + i * 8) * 512 + 256 + kh * 64 + h0 + tx];
    __syncthreads();
    for (int i = 0; i < 4; ++i)
        Vt[((size_t)bk * 64 + h0 + ty + i * 8) * 1024 + t0 + tx] = tile[tx][ty + i * 8];
}

// ---------- fused SDPA v3: LDS-staged K/V shared by the 4 GQA heads ----------
__global__ __launch_bounds__(256) void attn_kernel(const u16* __restrict__ Q,
                                                   const u16* __restrict__ KV,
                                                   const u16* __restrict__ Vt,
                                                   u16* __restrict__ O) {
    __shared__ __align__(16) u16 sK[2][64 * 64];
    __shared__ __align__(16) u16 sV[2][64 * 64];
    __shared__ __align__(16) u16 sP[4][16 * 64];
    const int tid = threadIdx.x, lane = tid & 63, w = tid >> 6;
    const int fr = lane & 15, fq = lane >> 4, frx = fr & 7;
    const int bk = blockIdx.x, b = bk >> 2, kh = bk & 3;
    const int h = kh * 4 + w;
    const int q0 = blockIdx.y * 16;
    const int qrow = b * 1024 + q0 + fr;

    const int srow = w * 16 + (lane >> 3);
    const int sslot = (lane & 7) ^ ((lane >> 3) & 7);
    const u16* gK = KV + (size_t)(b * 1024 + srow) * 512 + kh * 64 + sslot * 8;
    const u16* gV = Vt + (size_t)((b * 4 + kh) * 64 + srow) * 1024 + sslot * 8;
    u16* dK = (u16*)sK + w * 16 * 64;
    u16* dV = (u16*)sV + w * 16 * 64;

    bf16x8 qf[2];
    qf[0] = *(const bf16x8*)(Q + (size_t)qrow * 1024 + h * 64 + fq * 8);
    qf[1] = *(const bf16x8*)(Q + (size_t)qrow * 1024 + h * 64 + 32 + fq * 8);

    f32x4 oacc[4] = {};
    float mrun = -1e30f, lrun = 0.f;
    u16* sPw = sP[w];

    gload16(gK, dK);
    gload16(gK + (size_t)8 * 512, dK + 8 * 64);
    gload16(gV, dV);
    gload16(gV + (size_t)8 * 1024, dV + 8 * 64);
    __syncthreads();

    int cur = 0;
    for (int t = 0; t < 16; ++t) {
        const int kv0 = t * 64;
        if (t < 15) {
            const int kn = kv0 + 64;
            const int nx = (cur ^ 1) * 4096;
            gload16(gK + (size_t)kn * 512,       dK + nx);
            gload16(gK + (size_t)(kn + 8) * 512, dK + nx + 8 * 64);
            gload16(gV + kn,                     dV + nx);
            gload16(gV + kn + (size_t)8 * 1024,  dV + nx + 8 * 64);
        }
        const u16* sKc = (u16*)sK + cur * 4096;
        const u16* sVc = (u16*)sV + cur * 4096;
        f32x4 sacc[4] = {};
#pragma unroll
        for (int ks = 0; ks < 2; ++ks)
#pragma unroll
            for (int nb = 0; nb < 4; ++nb) {
                const bf16x8 kf = *(const bf16x8*)(
                    sKc + (nb * 16 + fr) * 64 + (((ks * 4 + fq) ^ frx) << 3));
                sacc[nb] = __builtin_amdgcn_mfma_f32_16x16x32_bf16(kf, qf[ks], sacc[nb], 0, 0, 0);
            }
        float pm;
        {
            float a0 = fmaxf(fmaxf(sacc[0][0], sacc[0][1]), fmaxf(sacc[0][2], sacc[0][3]));
            float a1 = fmaxf(fmaxf(sacc[1][0], sacc[1][1]), fmaxf(sacc[1][2], sacc[1][3]));
            float a2 = fmaxf(fmaxf(sacc[2][0], sacc[2][1]), fmaxf(sacc[2][2], sacc[2][3]));
            float a3 = fmaxf(fmaxf(sacc[3][0], sacc[3][1]), fmaxf(sacc[3][2], sacc[3][3]));
            pm = fmaxf(fmaxf(a0, a1), fmaxf(a2, a3));
        }
        pm = fmaxf(pm, __shfl_xor(pm, 16, 64));
        pm = fmaxf(pm, __shfl_xor(pm, 32, 64));
        if (!__all(pm <= mrun + 8.f)) {
            const float mn = fmaxf(mrun, pm);
            const float al = __expf(mrun - mn);
            mrun = mn;
            lrun *= al;
#pragma unroll
            for (int f = 0; f < 4; ++f) {
                f32x4 tt = oacc[f];
#pragma unroll
                for (int r = 0; r < 4; ++r) tt[r] *= al;
                oacc[f] = tt;
            }
        }
        float rs = 0.f;
#pragma unroll
        for (int nb = 0; nb < 4; ++nb) {
            union { uint2 u2; u16 hh[4]; } pk;
#pragma unroll
            for (int r = 0; r < 4; ++r) {
                const float p = __expf(sacc[nb][r] - mrun);
                rs += p;
                pk.hh[r] = f2bf(p);
            }
            const int slotl = nb * 2 + (fq >> 1);
            *(uint2*)(sPw + fr * 64 + (((slotl ^ frx) << 3) | ((fq & 1) << 2))) = pk.u2;
        }
        rs += __shfl_xor(rs, 16, 64);
        rs += __shfl_xor(rs, 32, 64);
        lrun += rs;
        asm volatile("s_waitcnt lgkmcnt(0)" ::: "memory");
        __builtin_amdgcn_sched_barrier(0);
#pragma unroll
        for (int ks2 = 0; ks2 < 2; ++ks2) {
            const bf16x8 pf = *(const bf16x8*)(
                sPw + fr * 64 + (((ks2 * 4 + fq) ^ frx) << 3));
#pragma unroll
            for (int f = 0; f < 4; ++f) {
                const bf16x8 vf = *(const bf16x8*)(
                    sVc + (f * 16 + fr) * 64 + (((ks2 * 4 + fq) ^ frx) << 3));
                oacc[f] = __builtin_amdgcn_mfma_f32_16x16x32_bf16(vf, pf, oacc[f], 0, 0, 0);
            }
        }
        __syncthreads();
        cur ^= 1;
    }

    const float linv = 1.f / lrun;
#pragma unroll
    for (int f = 0; f < 4; ++f) {
        union { uint2 u2; u16 hh[4]; } ok;
#pragma unroll
        for (int r = 0; r < 4; ++r) ok.hh[r] = f2bf(oacc[f][r] * linv);
        *(uint2*)(O + (size_t)qrow * 1024 + h * 64 + f * 16 + fq * 4) = ok.u2;
    }
}

// ---------- depthwise conv(K=31) + BN + SiLU ----------
__global__ __launch_bounds__(256) void dwconv_kernel(const u16* __restrict__ G,
                                                     const float* __restrict__ wt,
                                                     const float* __restrict__ wb,
                                                     const float* __restrict__ bg,
                                                     const float* __restrict__ bb,
                                                     const float* __restrict__ rm,
                                                     const float* __restrict__ rv,
                                                     u16* __restrict__ out) {
    __shared__ u16 sg[38 * 256];
    const int tid = threadIdx.x;
    const int d = blockIdx.x * 256 + tid;
    const int t0 = blockIdx.y * 8;
    const int b = blockIdx.z;
    const size_t base = (size_t)b * 1024 * 1024 + d;
    for (int i = 0; i < 38; ++i) {
        const int t = t0 - 15 + i;
        sg[i * 256 + tid] = (t >= 0 && t < 1024) ? G[base + (size_t)t * 1024] : (u16)0;
    }
    __syncthreads();
    float wreg[31];
#pragma unroll
    for (int k = 0; k < 31; ++k) wreg[k] = wt[d * 31 + k];
    const float scale = bg[d] * rsqrtf(rv[d] + 1e-5f);
    const float addv = wb[d] - rm[d];
#pragma unroll
    for (int j = 0; j < 8; ++j) {
        float acc = 0.f;
#pragma unroll
        for (int k = 0; k < 31; ++k) acc += bf2f(sg[(j + k) * 256 + tid]) * wreg[k];
        float y = (acc + addv) * scale + bb[d];
        y = y / (1.f + __expf(-y));               // silu
        out[base + (size_t)(t0 + j) * 1024] = f2bf(y);
    }
}

// =====================================================================
extern "C" void kernel_launch(void* const* d_in, const int* in_sizes, int n_in,
                              void* d_out, int out_size, void* d_ws, size_t ws_size,
                              hipStream_t stream) {
    (void)in_sizes; (void)n_in; (void)out_size;

    const float* x       = (const float*)d_in[0];
    const float* ff1_ng  = (const float*)d_in[1];
    const float* ff1_nb  = (const float*)d_in[2];
    const float* ff1_w1  = (const float*)d_in[3];
    const float* ff1_b1  = (const float*)d_in[4];
    const float* ff1_w2  = (const float*)d_in[5];
    const float* ff1_b2  = (const float*)d_in[6];
    const float* attn_ng = (const float*)d_in[7];
    const float* attn_nb = (const float*)d_in[8];
    const float* wq      = (const float*)d_in[9];
    const float* wkva    = (const float*)d_in[10];
    const float* kvn_g   = (const float*)d_in[11];
    const float* kvn_b   = (const float*)d_in[12];
    const float* wkvb    = (const float*)d_in[13];
    const float* wo      = (const float*)d_in[14];
    const float* conv_ng = (const float*)d_in[15];
    const float* conv_nb = (const float*)d_in[16];
    const float* pw1_w   = (const float*)d_in[17];
    const float* pw1_b   = (const float*)d_in[18];
    const float* dw_w    = (const float*)d_in[19];
    const float* dw_b    = (const float*)d_in[20];
    const float* bn_g    = (const float*)d_in[21];
    const float* bn_b    = (const float*)d_in[22];
    const float* bn_rm   = (const float*)d_in[23];
    const float* bn_rv   = (const float*)d_in[24];
    const float* pw2_w   = (const float*)d_in[25];
    const float* pw2_b   = (const float*)d_in[26];
    const float* ff2_ng  = (const float*)d_in[27];
    const float* ff2_nb  = (const float*)d_in[28];
    const float* ff2_w1  = (const float*)d_in[29];
    const float* ff2_b1  = (const float*)d_in[30];
    const float* ff2_w2  = (const float*)d_in[31];
    const float* ff2_b2  = (const float*)d_in[32];
    const float* fin_g   = (const float*)d_in[33];
    const float* fin_b   = (const float*)d_in[34];

    const int M = 8192;        // B*T
    char* ws = (char*)d_ws;
    size_t off = 0;
    auto alloc = [&](size_t bytes) {
        size_t o = off;
        off += (bytes + 255) & ~(size_t)255;
        return o;
    };
    const size_t o_ff1w1 = alloc((size_t)4096 * 1024 * 2);
    const size_t o_ff1w2 = alloc((size_t)1024 * 4096 * 2);
    const size_t o_wq    = alloc((size_t)1024 * 1024 * 2);
    const size_t o_wkva  = alloc((size_t)256 * 1024 * 2);
    const size_t o_wkvb  = alloc((size_t)512 * 256 * 2);
    const size_t o_wo    = alloc((size_t)1024 * 1024 * 2);
    const size_t o_pw1   = alloc((size_t)2048 * 1024 * 2);
    const size_t o_pw2   = alloc((size_t)1024 * 1024 * 2);
    const size_t o_ff2w1 = alloc((size_t)4096 * 1024 * 2);
    const size_t o_ff2w2 = alloc((size_t)1024 * 4096 * 2);
    const size_t o_ctab  = alloc((size_t)1024 * 32 * 4);
    const size_t o_stab  = alloc((size_t)1024 * 32 * 4);
    const size_t o_xres  = alloc((size_t)M * 1024 * 4);
    const size_t o_ln    = alloc((size_t)M * 1024 * 2);
    const size_t o_bufa  = alloc((size_t)64 * 1024 * 1024);
    if (ws_size < off) return;

    u16* BUFA = (u16*)(ws + o_bufa);
    u16* Qb    = BUFA;                                   // 16 MB
    u16* KVb   = (u16*)((char*)BUFA + (16u << 20));      // 8 MB
    float* KVA = (float*)((char*)BUFA + (24u << 20));    // 8 MB fp32
    u16* LAT   = (u16*)((char*)BUFA + (32u << 20));      // 4 MB
    u16* VT    = (u16*)((char*)BUFA + (36u << 20));      // 4 MB
    u16* OB    = (u16*)((char*)BUFA + (40u << 20));      // 16 MB
    u16* PW1G  = BUFA;                                   // 16 MB (GLU out)
    u16* CONVO = (u16*)((char*)BUFA + (16u << 20));      // 16 MB
    u16* HID   = BUFA;                                   // 64 MB (FFN phase)

    u16* WT_FF1W1 = (u16*)(ws + o_ff1w1);
    u16* WT_FF1W2 = (u16*)(ws + o_ff1w2);
    u16* WT_WQ    = (u16*)(ws + o_wq);
    u16* WT_WKVA  = (u16*)(ws + o_wkva);
    u16* WT_WKVB  = (u16*)(ws + o_wkvb);
    u16* WT_WO    = (u16*)(ws + o_wo);
    u16* WT_PW1   = (u16*)(ws + o_pw1);
    u16* WT_PW2   = (u16*)(ws + o_pw2);
    u16* WT_FF2W1 = (u16*)(ws + o_ff2w1);
    u16* WT_FF2W2 = (u16*)(ws + o_ff2w2);
    float* CT = (float*)(ws + o_ctab);
    float* ST = (float*)(ws + o_stab);
    float* XR = (float*)(ws + o_xres);
    u16* LNB  = (u16*)(ws + o_ln);

    // --- weight conversion ---
    wconvert_t<0><<<dim3(32, 128), 256, 0, stream>>>(ff1_w1, WT_FF1W1, 1024, 4096, 4096);
    wconvert_t<0><<<dim3(128, 32), 256, 0, stream>>>(ff1_w2, WT_FF1W2, 4096, 1024, 1024);
    wconvert_t<0><<<dim3(32, 32),  256, 0, stream>>>(wq,     WT_WQ,    1024, 1024, 1024);
    wconvert_t<0><<<dim3(32, 8),   256, 0, stream>>>(wkva,   WT_WKVA,  1024, 256,  320);
    wconvert_t<0><<<dim3(8, 16),   256, 0, stream>>>(wkvb,   WT_WKVB,  256,  512,  512);
    wconvert_t<0><<<dim3(32, 32),  256, 0, stream>>>(wo,     WT_WO,    1024, 1024, 1024);
    wconvert_t<1><<<dim3(32, 64),  256, 0, stream>>>(pw1_w,  WT_PW1,   1024, 2048, 2048);
    wconvert_t<0><<<dim3(32, 32),  256, 0, stream>>>(pw2_w,  WT_PW2,   1024, 1024, 1024);
    wconvert_t<0><<<dim3(32, 128), 256, 0, stream>>>(ff2_w1, WT_FF2W1, 1024, 4096, 4096);
    wconvert_t<0><<<dim3(128, 32), 256, 0, stream>>>(ff2_w2, WT_FF2W2, 4096, 1024, 1024);
    rope_tables_kernel<<<128, 256, 0, stream>>>(CT, ST);

    // --- FFN1 (macaron half) ---
    ln_kernel<0><<<M, 256, 0, stream>>>(x, ff1_ng, ff1_nb, LNB, 1024);
    gemm8p<1, 2><<<512, 512, 0, stream>>>(LNB, WT_FF1W1, ff1_b1, nullptr, 0.f, HID, M, 4096, 1024, 16);
    gemm8p<3, 4><<<256, 512, 0, stream>>>(HID, WT_FF1W2, ff1_b2, x, 0.5f, XR, M, 1024, 4096, 8);

    // --- attention (RMLA) ---
    ln_kernel<0><<<M, 256, 0, stream>>>(XR, attn_ng, attn_nb, LNB, 1024);
    gemm8p<0, 4><<<256, 512, 0, stream>>>(LNB, WT_WQ, nullptr, nullptr, 0.f, Qb, M, 1024, 1024, 8);
    gemm_bf16<2><<<128, 256, 0, stream>>>(LNB, WT_WKVA, nullptr, nullptr, 0.f, KVA, M, 256, 1024, 2);
    ln_kernel<0><<<M, 256, 0, stream>>>(KVA, kvn_g, kvn_b, LAT, 256);
    gemm_bf16<0><<<256, 256, 0, stream>>>(LAT, WT_WKVB, nullptr, nullptr, 0.f, KVb, M, 512, 256, 4);
    rope_kernel<<<16384, 256, 0, stream>>>(Qb, CT, ST, 15, 4, 1024, 0.125f);
    rope_kernel<<<4096, 256, 0, stream>>>(KVb, CT, ST, 3, 2, 512, 1.0f);
    vtranspose_kernel<<<dim3(32, 2, 32), 256, 0, stream>>>(KVb, VT);
    attn_kernel<<<dim3(32, 64), 256, 0, stream>>>(Qb, KVb, VT, OB);
    gemm8p<3, 4><<<256, 512, 0, stream>>>(OB, WT_WO, nullptr, XR, 1.f, XR, M, 1024, 1024, 8);

    // --- conv module (GLU fused into pw1 epilogue) ---
    ln_kernel<0><<<M, 256, 0, stream>>>(XR, conv_ng, conv_nb, LNB, 1024);
    gemm8p<4, 2><<<256, 512, 0, stream>>>(LNB, WT_PW1, pw1_b, nullptr, 0.f, PW1G, M, 2048, 1024, 8);
    dwconv_kernel<<<dim3(4, 128, 8), 256, 0, stream>>>(PW1G, dw_w, dw_b, bn_g, bn_b, bn_rm, bn_rv, CONVO);
    gemm8p<3, 4><<<256, 512, 0, stream>>>(CONVO, WT_PW2, pw2_b, XR, 1.f, XR, M, 1024, 1024, 8);

    // --- FFN2 (macaron half) ---
    ln_kernel<0><<<M, 256, 0, stream>>>(XR, ff2_ng, ff2_nb, LNB, 1024);
    gemm8p<1, 2><<<512, 512, 0, stream>>>(LNB, WT_FF2W1, ff2_b1, nullptr, 0.f, HID, M, 4096, 1024, 16);
    gemm8p<3, 4><<<256, 512, 0, stream>>>(HID, WT_FF2W2, ff2_b2, XR, 0.5f, XR, M, 1024, 4096, 8);

    // --- final LN -> d_out (fp32) ---
    ln_kernel<1><<<M, 256, 0, stream>>>(XR, fin_g, fin_b, d_out, 1024);
}

// Round 7
// 771.454 us; speedup vs baseline: 1.0166x; 1.0166x over previous
//
#include <hip/hip_runtime.h>
#include <stdint.h>

typedef unsigned short u16;
using bf16x8 = __attribute__((ext_vector_type(8))) __bf16;
using f32x4  = __attribute__((ext_vector_type(4))) float;

// ---------- helpers ----------
__device__ __forceinline__ u16 f2bf(float f) {
    uint32_t u = __float_as_uint(f);
    u += 0x7fffu + ((u >> 16) & 1u);          // round-to-nearest-even
    return (u16)(u >> 16);
}
__device__ __forceinline__ float bf2f(u16 u) {
    return __uint_as_float(((uint32_t)u) << 16);
}
__device__ __forceinline__ void gload16(const void* g, void* l) {
    // async global->LDS, 16B per lane; LDS dest = wave-uniform base + lane*16
    __builtin_amdgcn_global_load_lds(
        (__attribute__((address_space(1))) void*)(uintptr_t)g,
        (__attribute__((address_space(3))) void*)(uintptr_t)l,
        16, 0, 0);
}

// ---------- LayerNorm: fp32 in -> bf16 (mode 0) or fp32 (mode 1) out ----------
template <int OUTF32>
__global__ __launch_bounds__(256) void ln_kernel(const float* __restrict__ in,
                                                 const float* __restrict__ g,
                                                 const float* __restrict__ b,
                                                 void* __restrict__ out, int D) {
    const int row = blockIdx.x;
    const int tid = threadIdx.x;
    const float* x = in + (size_t)row * D;
    const int nv = D >> 8;                    // 4 for D=1024, 1 for D=256
    float v[4];
    float s1 = 0.f, s2 = 0.f;
    for (int i = 0; i < nv; ++i) {
        float t = x[tid + (i << 8)];
        v[i] = t; s1 += t; s2 += t * t;
    }
    for (int o = 1; o < 64; o <<= 1) {
        s1 += __shfl_xor(s1, o, 64);
        s2 += __shfl_xor(s2, o, 64);
    }
    __shared__ float r1[4], r2[4];
    const int w = tid >> 6;
    if ((tid & 63) == 0) { r1[w] = s1; r2[w] = s2; }
    __syncthreads();
    s1 = r1[0] + r1[1] + r1[2] + r1[3];
    s2 = r2[0] + r2[1] + r2[2] + r2[3];
    const float mean = s1 / (float)D;
    const float var  = s2 / (float)D - mean * mean;
    const float inv  = rsqrtf(var + 1e-5f);
    for (int i = 0; i < nv; ++i) {
        int c = tid + (i << 8);
        float y = (v[i] - mean) * inv * g[c] + b[c];
        if (OUTF32) ((float*)out)[(size_t)row * D + c] = y;
        else        ((u16*)out)[(size_t)row * D + c] = f2bf(y);
    }
}

// ---------- weight transpose + fp32->bf16 convert (z selects one of 2 jobs) ----------
template <int GLUPERM>
__global__ __launch_bounds__(256) void wconvert_t(const float* __restrict__ W0,
                                                  u16* __restrict__ Wt0,
                                                  const float* __restrict__ W1,
                                                  u16* __restrict__ Wt1,
                                                  int K, int N, int ldw) {
    const float* W = blockIdx.z ? W1 : W0;
    u16* Wt = blockIdx.z ? Wt1 : Wt0;
    __shared__ float tile[32][33];
    const int k0 = blockIdx.x * 32, n0 = blockIdx.y * 32;
    const int tx = threadIdx.x & 31, ty = threadIdx.x >> 5;  // 32 x 8
    const int csrc = GLUPERM ? ((tx & 1) * 1024 + (n0 >> 1) + (tx >> 1)) : (n0 + tx);
    for (int i = 0; i < 4; ++i)
        tile[ty + i * 8][tx] = W[(size_t)(k0 + ty + i * 8) * ldw + csrc];
    __syncthreads();
    for (int i = 0; i < 4; ++i)
        Wt[(size_t)(n0 + ty + i * 8) * K + k0 + tx] = f2bf(tile[tx][ty + i * 8]);
}

// ========= GEMM 128x128, 4 waves, dbuf + counted vmcnt, 2 blocks/CU =========
// C[M,N] = A[M,K](bf16) * Bt[N,K](bf16)^T. BK=64, LDS 64KB -> 2 blocks/CU so
// one block's MFMAs cover the sibling's barrier/vmcnt drains (m114 TLP).
// Sync ledger: reads of buf finish (lgkm0 per wave + barrier) BEFORE stage
// overwrites buf; vmcnt(8) after MFMA waits tile s+1 only (s+2's 8 loads stay
// in flight across the barrier); tail drains 0.
// EPI: 0 bf16(+bias) ; 1 silu bf16(+bias) ; 2 f32(+bias) ;
//      3 f32 res + rscale*(acc+bias) ; 4 GLU pairs -> bf16 [M][N/2] ;
//      5 rope(all cols)*rscale -> bf16 ; 6 rope(cols<256) else plain -> bf16
template <int EPI>
__global__ __launch_bounds__(256, 2) void gemm128p(const u16* __restrict__ A,
                                                   const u16* __restrict__ Bt,
                                                   const float* __restrict__ bias,
                                                   const float* __restrict__ res,
                                                   float rscale,
                                                   void* __restrict__ outp,
                                                   const float* __restrict__ CT,
                                                   const float* __restrict__ ST,
                                                   int M, int N, int K, int nbx) {
    __shared__ u16 sA[2][128 * 64];
    __shared__ u16 sB[2][128 * 64];
    const int tid = threadIdx.x, lane = tid & 63, w = tid >> 6;
    const int wm = w >> 1, wn = w & 1;        // 2x2 wave grid
    const int fr = lane & 15, fq = lane >> 4, frx = fr & 7;
    const int cpx = gridDim.x >> 3;           // bijective XCD swizzle (grid%8==0)
    const int lid = (blockIdx.x & 7) * cpx + (blockIdx.x >> 3);
    const int bn0 = (lid % nbx) * 128;
    const int bm0 = (lid / nbx) * 128;

    f32x4 acc[4][4] = {};

    // staging: 4 gloads/wave per matrix per K-tile; pre-swizzled global source
    const int lrow = lane >> 3;
    const int lslot = (lane & 7) ^ lrow;
    const u16* ga0 = A  + (size_t)(bm0 + w * 8 + lrow) * K + lslot * 8;
    const u16* gb0 = Bt + (size_t)(bn0 + w * 8 + lrow) * K + lslot * 8;
    const size_t rstep32 = (size_t)32 * K;
    const int NK = K >> 6;

#define STAGE(bufi, kt)                                                         \
    {                                                                           \
        _Pragma("unroll")                                                       \
        for (int i = 0; i < 4; ++i) {                                           \
            gload16(ga0 + (kt) + i * rstep32, &sA[bufi][w * 512 + i * 2048]);   \
            gload16(gb0 + (kt) + i * rstep32, &sB[bufi][w * 512 + i * 2048]);   \
        }                                                                       \
    }
#define SB() __builtin_amdgcn_sched_barrier(0)

    // prologue: tiles 0,1 in flight; wait tile 0 only (8 of 16 outstanding)
    STAGE(0, 0)
    STAGE(1, 64)
    asm volatile("s_waitcnt vmcnt(8)" ::: "memory");
    SB();
    __builtin_amdgcn_s_barrier();

    for (int s = 0; s < NK; ++s) {
        const int buf = s & 1;
        bf16x8 afr[4], bfr[4], afr2[4], bfr2[4];
        // ---- kk0 reads + MFMA ----
#pragma unroll
        for (int i = 0; i < 4; ++i) {
            afr[i] = *(const bf16x8*)(&sA[buf][(wm * 64 + i * 16 + fr) * 64 + ((fq ^ frx) << 3)]);
            bfr[i] = *(const bf16x8*)(&sB[buf][(wn * 64 + i * 16 + fr) * 64 + ((fq ^ frx) << 3)]);
        }
        asm volatile("s_waitcnt lgkmcnt(0)" ::: "memory");
        SB();
        __builtin_amdgcn_s_setprio(1);
#pragma unroll
        for (int mi = 0; mi < 4; ++mi)
#pragma unroll
            for (int ni = 0; ni < 4; ++ni)
                acc[mi][ni] = __builtin_amdgcn_mfma_f32_16x16x32_bf16(
                    bfr[ni], afr[mi], acc[mi][ni], 0, 0, 0);   // D[n][m]
        __builtin_amdgcn_s_setprio(0);
        // ---- kk1 reads (finish all reads of buf) ----
#pragma unroll
        for (int i = 0; i < 4; ++i) {
            afr2[i] = *(const bf16x8*)(&sA[buf][(wm * 64 + i * 16 + fr) * 64 + (((4 + fq) ^ frx) << 3)]);
            bfr2[i] = *(const bf16x8*)(&sB[buf][(wn * 64 + i * 16 + fr) * 64 + (((4 + fq) ^ frx) << 3)]);
        }
        asm volatile("s_waitcnt lgkmcnt(0)" ::: "memory");
        SB();
        __builtin_amdgcn_s_barrier();          // all waves done reading buf
        if (s + 2 < NK) STAGE(buf, (s + 2) << 6)  // overwrite drained buf
        SB();
        __builtin_amdgcn_s_setprio(1);
#pragma unroll
        for (int mi = 0; mi < 4; ++mi)
#pragma unroll
            for (int ni = 0; ni < 4; ++ni)
                acc[mi][ni] = __builtin_amdgcn_mfma_f32_16x16x32_bf16(
                    bfr2[ni], afr2[mi], acc[mi][ni], 0, 0, 0);
        __builtin_amdgcn_s_setprio(0);
        // wait tile s+1 landed (tile s+2's 8 loads stay in flight)
        if (s + 2 < NK) { asm volatile("s_waitcnt vmcnt(8)" ::: "memory"); }
        else            { asm volatile("s_waitcnt vmcnt(0)" ::: "memory"); }
        SB();
        __builtin_amdgcn_s_barrier();          // buf^1 ready for next step
    }

    // epilogue: lane holds rows m = bm0+wm*64+mi*16+fr, cols n0..n0+3
#pragma unroll
    for (int mi = 0; mi < 4; ++mi) {
        const int m = bm0 + wm * 64 + mi * 16 + fr;
        if (EPI == 5 || EPI == 6) {
            const int t = m & 1023;
            const int colbase = bn0 + wn * 64;
            const bool dorope = (EPI == 5) || (colbase < 256);
            if (dorope) {
#pragma unroll
                for (int ni = 0; ni < 2; ++ni) {
                    const int j0 = ni * 16 + fq * 4;       // in-head col (0..31)
                    const f32x4 c = *(const f32x4*)(CT + t * 32 + j0);
                    const f32x4 sn = *(const f32x4*)(ST + t * 32 + j0);
                    union { uint2 u2; u16 hh[4]; } o1, o2;
#pragma unroll
                    for (int r = 0; r < 4; ++r) {
                        const float x1 = acc[mi][ni][r];
                        const float x2 = acc[mi][ni + 2][r];
                        o1.hh[r] = f2bf((x1 * c[r] - x2 * sn[r]) * rscale);
                        o2.hh[r] = f2bf((x2 * c[r] + x1 * sn[r]) * rscale);
                    }
                    *(uint2*)((u16*)outp + (size_t)m * N + colbase + j0) = o1.u2;
                    *(uint2*)((u16*)outp + (size_t)m * N + colbase + j0 + 32) = o2.u2;
                }
            } else {
#pragma unroll
                for (int ni = 0; ni < 4; ++ni) {
                    const int n0 = colbase + ni * 16 + fq * 4;
                    union { uint2 u2; u16 hh[4]; } ok;
#pragma unroll
                    for (int r = 0; r < 4; ++r) ok.hh[r] = f2bf(acc[mi][ni][r]);
                    *(uint2*)((u16*)outp + (size_t)m * N + n0) = ok.u2;
                }
            }
            continue;
        }
#pragma unroll
        for (int ni = 0; ni < 4; ++ni) {
            const int n0 = bn0 + wn * 64 + ni * 16 + fq * 4;
            if (EPI == 0 || EPI == 1) {
                union { uint2 u2; u16 hh[4]; } ok;
#pragma unroll
                for (int r = 0; r < 4; ++r) {
                    float v = acc[mi][ni][r] + (bias ? bias[n0 + r] : 0.f);
                    if (EPI == 1) v = v / (1.f + __expf(-v));
                    ok.hh[r] = f2bf(v);
                }
                *(uint2*)((u16*)outp + (size_t)m * N + n0) = ok.u2;
            } else if (EPI == 2) {
                f32x4 v;
#pragma unroll
                for (int r = 0; r < 4; ++r)
                    v[r] = acc[mi][ni][r] + (bias ? bias[n0 + r] : 0.f);
                *(f32x4*)((float*)outp + (size_t)m * N + n0) = v;
            } else if (EPI == 3) {
                const f32x4 rv = *(const f32x4*)(res + (size_t)m * N + n0);
                f32x4 v;
#pragma unroll
                for (int r = 0; r < 4; ++r)
                    v[r] = rv[r] + rscale * (acc[mi][ni][r] + (bias ? bias[n0 + r] : 0.f));
                *(f32x4*)((float*)outp + (size_t)m * N + n0) = v;
            } else if (EPI == 4) {             // GLU pairs (interleaved cols)
                float vv[4];
#pragma unroll
                for (int r = 0; r < 4; ++r) {
                    const int n = n0 + r;
                    vv[r] = acc[mi][ni][r] + bias[((n & 1) << 10) + (n >> 1)];
                }
                union { uint32_t u; u16 hh[2]; } ok;
                ok.hh[0] = f2bf(vv[0] / (1.f + __expf(-vv[1])));
                ok.hh[1] = f2bf(vv[2] / (1.f + __expf(-vv[3])));
                *(uint32_t*)((u16*)outp + (size_t)m * (N >> 1) + (n0 >> 1)) = ok.u;
            }
        }
    }
#undef STAGE
#undef SB
}

// ---------- RoPE tables ----------
__global__ __launch_bounds__(256) void rope_tables_kernel(float* __restrict__ ct,
                                                          float* __restrict__ st) {
    const int i = blockIdx.x * 256 + threadIdx.x;   // 32768
    const int t = i >> 5, j = i & 31;
    const float inv = powf(10000.f, -(float)j / 32.f);
    const float f = (float)t * inv;
    ct[i] = cosf(f);
    st[i] = sinf(f);
}

// ---------- V transpose ----------
__global__ __launch_bounds__(256) void vtranspose_kernel(const u16* __restrict__ KV,
                                                         u16* __restrict__ Vt) {
    __shared__ u16 tile[32][33];
    const int t0 = blockIdx.x * 32, h0 = blockIdx.y * 32;
    const int bk = blockIdx.z;                 // b*4 + kh
    const int b = bk >> 2, kh = bk & 3;
    const int tx = threadIdx.x & 31, ty = threadIdx.x >> 5;
    for (int i = 0; i < 4; ++i)
        tile[ty + i * 8][tx] =
            KV[(size_t)(b * 1024 + t0 + ty + i * 8) * 512 + 256 + kh * 64 + h0 + tx];
    __syncthreads();
    for (int i = 0; i < 4; ++i)
        Vt[((size_t)bk * 64 + h0 + ty + i * 8) * 1024 + t0 + tx] = tile[tx][ty + i * 8];
}

// ---------- fused SDPA v3: LDS-staged K/V shared by the 4 GQA heads ----------
__global__ __launch_bounds__(256) void attn_kernel(const u16* __restrict__ Q,
                                                   const u16* __restrict__ KV,
                                                   const u16* __restrict__ Vt,
                                                   u16* __restrict__ O) {
    __shared__ __align__(16) u16 sK[2][64 * 64];
    __shared__ __align__(16) u16 sV[2][64 * 64];
    __shared__ __align__(16) u16 sP[4][16 * 64];
    const int tid = threadIdx.x, lane = tid & 63, w = tid >> 6;
    const int fr = lane & 15, fq = lane >> 4, frx = fr & 7;
    const int bk = blockIdx.x, b = bk >> 2, kh = bk & 3;
    const int h = kh * 4 + w;
    const int q0 = blockIdx.y * 16;
    const int qrow = b * 1024 + q0 + fr;

    const int srow = w * 16 + (lane >> 3);
    const int sslot = (lane & 7) ^ ((lane >> 3) & 7);
    const u16* gK = KV + (size_t)(b * 1024 + srow) * 512 + kh * 64 + sslot * 8;
    const u16* gV = Vt + (size_t)((b * 4 + kh) * 64 + srow) * 1024 + sslot * 8;
    u16* dK = (u16*)sK + w * 16 * 64;
    u16* dV = (u16*)sV + w * 16 * 64;

    bf16x8 qf[2];
    qf[0] = *(const bf16x8*)(Q + (size_t)qrow * 1024 + h * 64 + fq * 8);
    qf[1] = *(const bf16x8*)(Q + (size_t)qrow * 1024 + h * 64 + 32 + fq * 8);

    f32x4 oacc[4] = {};
    float mrun = -1e30f, lrun = 0.f;
    u16* sPw = sP[w];

    gload16(gK, dK);
    gload16(gK + (size_t)8 * 512, dK + 8 * 64);
    gload16(gV, dV);
    gload16(gV + (size_t)8 * 1024, dV + 8 * 64);
    __syncthreads();

    int cur = 0;
    for (int t = 0; t < 16; ++t) {
        const int kv0 = t * 64;
        if (t < 15) {
            const int kn = kv0 + 64;
            const int nx = (cur ^ 1) * 4096;
            gload16(gK + (size_t)kn * 512,       dK + nx);
            gload16(gK + (size_t)(kn + 8) * 512, dK + nx + 8 * 64);
            gload16(gV + kn,                     dV + nx);
            gload16(gV + kn + (size_t)8 * 1024,  dV + nx + 8 * 64);
        }
        const u16* sKc = (u16*)sK + cur * 4096;
        const u16* sVc = (u16*)sV + cur * 4096;
        f32x4 sacc[4] = {};
#pragma unroll
        for (int ks = 0; ks < 2; ++ks)
#pragma unroll
            for (int nb = 0; nb < 4; ++nb) {
                const bf16x8 kf = *(const bf16x8*)(
                    sKc + (nb * 16 + fr) * 64 + (((ks * 4 + fq) ^ frx) << 3));
                sacc[nb] = __builtin_amdgcn_mfma_f32_16x16x32_bf16(kf, qf[ks], sacc[nb], 0, 0, 0);
            }
        float pm;
        {
            float a0 = fmaxf(fmaxf(sacc[0][0], sacc[0][1]), fmaxf(sacc[0][2], sacc[0][3]));
            float a1 = fmaxf(fmaxf(sacc[1][0], sacc[1][1]), fmaxf(sacc[1][2], sacc[1][3]));
            float a2 = fmaxf(fmaxf(sacc[2][0], sacc[2][1]), fmaxf(sacc[2][2], sacc[2][3]));
            float a3 = fmaxf(fmaxf(sacc[3][0], sacc[3][1]), fmaxf(sacc[3][2], sacc[3][3]));
            pm = fmaxf(fmaxf(a0, a1), fmaxf(a2, a3));
        }
        pm = fmaxf(pm, __shfl_xor(pm, 16, 64));
        pm = fmaxf(pm, __shfl_xor(pm, 32, 64));
        if (!__all(pm <= mrun + 8.f)) {
            const float mn = fmaxf(mrun, pm);
            const float al = __expf(mrun - mn);
            mrun = mn;
            lrun *= al;
#pragma unroll
            for (int f = 0; f < 4; ++f) {
                f32x4 tt = oacc[f];
#pragma unroll
                for (int r = 0; r < 4; ++r) tt[r] *= al;
                oacc[f] = tt;
            }
        }
        float rs = 0.f;
#pragma unroll
        for (int nb = 0; nb < 4; ++nb) {
            union { uint2 u2; u16 hh[4]; } pk;
#pragma unroll
            for (int r = 0; r < 4; ++r) {
                const float p = __expf(sacc[nb][r] - mrun);
                rs += p;
                pk.hh[r] = f2bf(p);
            }
            const int slotl = nb * 2 + (fq >> 1);
            *(uint2*)(sPw + fr * 64 + (((slotl ^ frx) << 3) | ((fq & 1) << 2))) = pk.u2;
        }
        rs += __shfl_xor(rs, 16, 64);
        rs += __shfl_xor(rs, 32, 64);
        lrun += rs;
        asm volatile("s_waitcnt lgkmcnt(0)" ::: "memory");
        __builtin_amdgcn_sched_barrier(0);
#pragma unroll
        for (int ks2 = 0; ks2 < 2; ++ks2) {
            const bf16x8 pf = *(const bf16x8*)(
                sPw + fr * 64 + (((ks2 * 4 + fq) ^ frx) << 3));
#pragma unroll
            for (int f = 0; f < 4; ++f) {
                const bf16x8 vf = *(const bf16x8*)(
                    sVc + (f * 16 + fr) * 64 + (((ks2 * 4 + fq) ^ frx) << 3));
                oacc[f] = __builtin_amdgcn_mfma_f32_16x16x32_bf16(vf, pf, oacc[f], 0, 0, 0);
            }
        }
        __syncthreads();
        cur ^= 1;
    }

    const float linv = 1.f / lrun;
#pragma unroll
    for (int f = 0; f < 4; ++f) {
        union { uint2 u2; u16 hh[4]; } ok;
#pragma unroll
        for (int r = 0; r < 4; ++r) ok.hh[r] = f2bf(oacc[f][r] * linv);
        *(uint2*)(O + (size_t)qrow * 1024 + h * 64 + f * 16 + fq * 4) = ok.u2;
    }
}

// ---------- depthwise conv(K=31) + BN + SiLU ----------
__global__ __launch_bounds__(256) void dwconv_kernel(const u16* __restrict__ G,
                                                     const float* __restrict__ wt,
                                                     const float* __restrict__ wb,
                                                     const float* __restrict__ bg,
                                                     const float* __restrict__ bb,
                                                     const float* __restrict__ rm,
                                                     const float* __restrict__ rv,
                                                     u16* __restrict__ out) {
    __shared__ u16 sg[38 * 256];
    const int tid = threadIdx.x;
    const int d = blockIdx.x * 256 + tid;
    const int t0 = blockIdx.y * 8;
    const int b = blockIdx.z;
    const size_t base = (size_t)b * 1024 * 1024 + d;
    for (int i = 0; i < 38; ++i) {
        const int t = t0 - 15 + i;
        sg[i * 256 + tid] = (t >= 0 && t < 1024) ? G[base + (size_t)t * 1024] : (u16)0;
    }
    __syncthreads();
    float wreg[31];
#pragma unroll
    for (int k = 0; k < 31; ++k) wreg[k] = wt[d * 31 + k];
    const float scale = bg[d] * rsqrtf(rv[d] + 1e-5f);
    const float addv = wb[d] - rm[d];
#pragma unroll
    for (int j = 0; j < 8; ++j) {
        float acc = 0.f;
#pragma unroll
        for (int k = 0; k < 31; ++k) acc += bf2f(sg[(j + k) * 256 + tid]) * wreg[k];
        float y = (acc + addv) * scale + bb[d];
        y = y / (1.f + __expf(-y));               // silu
        out[base + (size_t)(t0 + j) * 1024] = f2bf(y);
    }
}

// =====================================================================
extern "C" void kernel_launch(void* const* d_in, const int* in_sizes, int n_in,
                              void* d_out, int out_size, void* d_ws, size_t ws_size,
                              hipStream_t stream) {
    (void)in_sizes; (void)n_in; (void)out_size;

    const float* x       = (const float*)d_in[0];
    const float* ff1_ng  = (const float*)d_in[1];
    const float* ff1_nb  = (const float*)d_in[2];
    const float* ff1_w1  = (const float*)d_in[3];
    const float* ff1_b1  = (const float*)d_in[4];
    const float* ff1_w2  = (const float*)d_in[5];
    const float* ff1_b2  = (const float*)d_in[6];
    const float* attn_ng = (const float*)d_in[7];
    const float* attn_nb = (const float*)d_in[8];
    const float* wq      = (const float*)d_in[9];
    const float* wkva    = (const float*)d_in[10];
    const float* kvn_g   = (const float*)d_in[11];
    const float* kvn_b   = (const float*)d_in[12];
    const float* wkvb    = (const float*)d_in[13];
    const float* wo      = (const float*)d_in[14];
    const float* conv_ng = (const float*)d_in[15];
    const float* conv_nb = (const float*)d_in[16];
    const float* pw1_w   = (const float*)d_in[17];
    const float* pw1_b   = (const float*)d_in[18];
    const float* dw_w    = (const float*)d_in[19];
    const float* dw_b    = (const float*)d_in[20];
    const float* bn_g    = (const float*)d_in[21];
    const float* bn_b    = (const float*)d_in[22];
    const float* bn_rm   = (const float*)d_in[23];
    const float* bn_rv   = (const float*)d_in[24];
    const float* pw2_w   = (const float*)d_in[25];
    const float* pw2_b   = (const float*)d_in[26];
    const float* ff2_ng  = (const float*)d_in[27];
    const float* ff2_nb  = (const float*)d_in[28];
    const float* ff2_w1  = (const float*)d_in[29];
    const float* ff2_b1  = (const float*)d_in[30];
    const float* ff2_w2  = (const float*)d_in[31];
    const float* ff2_b2  = (const float*)d_in[32];
    const float* fin_g   = (const float*)d_in[33];
    const float* fin_b   = (const float*)d_in[34];

    const int M = 8192;        // B*T
    char* ws = (char*)d_ws;
    size_t off = 0;
    auto alloc = [&](size_t bytes) {
        size_t o = off;
        off += (bytes + 255) & ~(size_t)255;
        return o;
    };
    const size_t o_ff1w1 = alloc((size_t)4096 * 1024 * 2);
    const size_t o_ff1w2 = alloc((size_t)1024 * 4096 * 2);
    const size_t o_wq    = alloc((size_t)1024 * 1024 * 2);
    const size_t o_wkva  = alloc((size_t)256 * 1024 * 2);
    const size_t o_wkvb  = alloc((size_t)512 * 256 * 2);
    const size_t o_wo    = alloc((size_t)1024 * 1024 * 2);
    const size_t o_pw1   = alloc((size_t)2048 * 1024 * 2);
    const size_t o_pw2   = alloc((size_t)1024 * 1024 * 2);
    const size_t o_ff2w1 = alloc((size_t)4096 * 1024 * 2);
    const size_t o_ff2w2 = alloc((size_t)1024 * 4096 * 2);
    const size_t o_ctab  = alloc((size_t)1024 * 32 * 4);
    const size_t o_stab  = alloc((size_t)1024 * 32 * 4);
    const size_t o_xres  = alloc((size_t)M * 1024 * 4);
    const size_t o_ln    = alloc((size_t)M * 1024 * 2);
    const size_t o_bufa  = alloc((size_t)64 * 1024 * 1024);
    if (ws_size < off) return;

    u16* BUFA = (u16*)(ws + o_bufa);
    u16* Qb    = BUFA;                                   // 16 MB
    u16* KVb   = (u16*)((char*)BUFA + (16u << 20));      // 8 MB
    float* KVA = (float*)((char*)BUFA + (24u << 20));    // 8 MB fp32
    u16* LAT   = (u16*)((char*)BUFA + (32u << 20));      // 4 MB
    u16* VT    = (u16*)((char*)BUFA + (36u << 20));      // 4 MB
    u16* OB    = (u16*)((char*)BUFA + (40u << 20));      // 16 MB
    u16* PW1G  = BUFA;                                   // 16 MB (GLU out)
    u16* CONVO = (u16*)((char*)BUFA + (16u << 20));      // 16 MB
    u16* HID   = BUFA;                                   // 64 MB (FFN phase)

    u16* WT_FF1W1 = (u16*)(ws + o_ff1w1);
    u16* WT_FF1W2 = (u16*)(ws + o_ff1w2);
    u16* WT_WQ    = (u16*)(ws + o_wq);
    u16* WT_WKVA  = (u16*)(ws + o_wkva);
    u16* WT_WKVB  = (u16*)(ws + o_wkvb);
    u16* WT_WO    = (u16*)(ws + o_wo);
    u16* WT_PW1   = (u16*)(ws + o_pw1);
    u16* WT_PW2   = (u16*)(ws + o_pw2);
    u16* WT_FF2W1 = (u16*)(ws + o_ff2w1);
    u16* WT_FF2W2 = (u16*)(ws + o_ff2w2);
    float* CT = (float*)(ws + o_ctab);
    float* ST = (float*)(ws + o_stab);
    float* XR = (float*)(ws + o_xres);
    u16* LNB  = (u16*)(ws + o_ln);

    // --- weight conversion (paired where shapes match) ---
    wconvert_t<0><<<dim3(32, 128, 2), 256, 0, stream>>>(ff1_w1, WT_FF1W1, ff2_w1, WT_FF2W1, 1024, 4096, 4096);
    wconvert_t<0><<<dim3(128, 32, 2), 256, 0, stream>>>(ff1_w2, WT_FF1W2, ff2_w2, WT_FF2W2, 4096, 1024, 1024);
    wconvert_t<0><<<dim3(32, 32, 2),  256, 0, stream>>>(wq, WT_WQ, wo, WT_WO, 1024, 1024, 1024);
    wconvert_t<0><<<dim3(32, 32, 1),  256, 0, stream>>>(pw2_w, WT_PW2, pw2_w, WT_PW2, 1024, 1024, 1024);
    wconvert_t<0><<<dim3(32, 8, 1),   256, 0, stream>>>(wkva, WT_WKVA, wkva, WT_WKVA, 1024, 256, 320);
    wconvert_t<0><<<dim3(8, 16, 1),   256, 0, stream>>>(wkvb, WT_WKVB, wkvb, WT_WKVB, 256, 512, 512);
    wconvert_t<1><<<dim3(32, 64, 1),  256, 0, stream>>>(pw1_w, WT_PW1, pw1_w, WT_PW1, 1024, 2048, 2048);
    rope_tables_kernel<<<128, 256, 0, stream>>>(CT, ST);

    // --- FFN1 (macaron half) ---
    ln_kernel<0><<<M, 256, 0, stream>>>(x, ff1_ng, ff1_nb, LNB, 1024);
    gemm128p<1><<<2048, 256, 0, stream>>>(LNB, WT_FF1W1, ff1_b1, nullptr, 0.f, HID, nullptr, nullptr, M, 4096, 1024, 32);
    gemm128p<3><<<512, 256, 0, stream>>>(HID, WT_FF1W2, ff1_b2, x, 0.5f, XR, nullptr, nullptr, M, 1024, 4096, 8);

    // --- attention (RMLA); RoPE fused into wq / wkvb epilogues ---
    ln_kernel<0><<<M, 256, 0, stream>>>(XR, attn_ng, attn_nb, LNB, 1024);
    gemm128p<5><<<512, 256, 0, stream>>>(LNB, WT_WQ, nullptr, nullptr, 0.125f, Qb, CT, ST, M, 1024, 1024, 8);
    gemm128p<2><<<128, 256, 0, stream>>>(LNB, WT_WKVA, nullptr, nullptr, 0.f, KVA, nullptr, nullptr, M, 256, 1024, 2);
    ln_kernel<0><<<M, 256, 0, stream>>>(KVA, kvn_g, kvn_b, LAT, 256);
    gemm128p<6><<<256, 256, 0, stream>>>(LAT, WT_WKVB, nullptr, nullptr, 1.0f, KVb, CT, ST, M, 512, 256, 4);
    vtranspose_kernel<<<dim3(32, 2, 32), 256, 0, stream>>>(KVb, VT);
    attn_kernel<<<dim3(32, 64), 256, 0, stream>>>(Qb, KVb, VT, OB);
    gemm128p<3><<<512, 256, 0, stream>>>(OB, WT_WO, nullptr, XR, 1.f, XR, nullptr, nullptr, M, 1024, 1024, 8);

    // --- conv module (GLU fused into pw1 epilogue) ---
    ln_kernel<0><<<M, 256, 0, stream>>>(XR, conv_ng, conv_nb, LNB, 1024);
    gemm128p<4><<<1024, 256, 0, stream>>>(LNB, WT_PW1, pw1_b, nullptr, 0.f, PW1G, nullptr, nullptr, M, 2048, 1024, 16);
    dwconv_kernel<<<dim3(4, 128, 8), 256, 0, stream>>>(PW1G, dw_w, dw_b, bn_g, bn_b, bn_rm, bn_rv, CONVO);
    gemm128p<3><<<512, 256, 0, stream>>>(CONVO, WT_PW2, pw2_b, XR, 1.f, XR, nullptr, nullptr, M, 1024, 1024, 8);

    // --- FFN2 (macaron half) ---
    ln_kernel<0><<<M, 256, 0, stream>>>(XR, ff2_ng, ff2_nb, LNB, 1024);
    gemm128p<1><<<2048, 256, 0, stream>>>(LNB, WT_FF2W1, ff2_b1, nullptr, 0.f, HID, nullptr, nullptr, M, 4096, 1024, 32);
    gemm128p<3><<<512, 256, 0, stream>>>(HID, WT_FF2W2, ff2_b2, XR, 0.5f, XR, nullptr, nullptr, M, 1024, 4096, 8);

    // --- final LN -> d_out (fp32) ---
    ln_kernel<1><<<M, 256, 0, stream>>>(XR, fin_g, fin_b, d_out, 1024);
}

// Round 9
// 731.495 us; speedup vs baseline: 1.0721x; 1.0546x over previous
//
#include <hip/hip_runtime.h>
#include <stdint.h>

typedef unsigned short u16;
using bf16x8 = __attribute__((ext_vector_type(8))) __bf16;
using f32x4  = __attribute__((ext_vector_type(4))) float;

// ---------- helpers ----------
__device__ __forceinline__ u16 f2bf(float f) {
    uint32_t u = __float_as_uint(f);
    u += 0x7fffu + ((u >> 16) & 1u);          // round-to-nearest-even
    return (u16)(u >> 16);
}
__device__ __forceinline__ float bf2f(u16 u) {
    return __uint_as_float(((uint32_t)u) << 16);
}
__device__ __forceinline__ void gload16(const void* g, void* l) {
    __builtin_amdgcn_global_load_lds(
        (__attribute__((address_space(1))) void*)(uintptr_t)g,
        (__attribute__((address_space(3))) void*)(uintptr_t)l,
        16, 0, 0);
}

// ---------- LayerNorm: fp32 in -> bf16 (mode 0) or fp32 (mode 1) out ----------
template <int OUTF32>
__global__ __launch_bounds__(256) void ln_kernel(const float* __restrict__ in,
                                                 const float* __restrict__ g,
                                                 const float* __restrict__ b,
                                                 void* __restrict__ out, int D) {
    const int row = blockIdx.x;
    const int tid = threadIdx.x;
    const float* x = in + (size_t)row * D;
    const int nv = D >> 8;
    float v[4];
    float s1 = 0.f, s2 = 0.f;
    for (int i = 0; i < nv; ++i) {
        float t = x[tid + (i << 8)];
        v[i] = t; s1 += t; s2 += t * t;
    }
    for (int o = 1; o < 64; o <<= 1) {
        s1 += __shfl_xor(s1, o, 64);
        s2 += __shfl_xor(s2, o, 64);
    }
    __shared__ float r1[4], r2[4];
    const int w = tid >> 6;
    if ((tid & 63) == 0) { r1[w] = s1; r2[w] = s2; }
    __syncthreads();
    s1 = r1[0] + r1[1] + r1[2] + r1[3];
    s2 = r2[0] + r2[1] + r2[2] + r2[3];
    const float mean = s1 / (float)D;
    const float var  = s2 / (float)D - mean * mean;
    const float inv  = rsqrtf(var + 1e-5f);
    for (int i = 0; i < nv; ++i) {
        int c = tid + (i << 8);
        float y = (v[i] - mean) * inv * g[c] + b[c];
        if (OUTF32) ((float*)out)[(size_t)row * D + c] = y;
        else        ((u16*)out)[(size_t)row * D + c] = f2bf(y);
    }
}

// ---------- weight transpose + fp32->bf16 convert (z selects one of 2 jobs) ----------
template <int GLUPERM>
__global__ __launch_bounds__(256) void wconvert_t(const float* __restrict__ W0,
                                                  u16* __restrict__ Wt0,
                                                  const float* __restrict__ W1,
                                                  u16* __restrict__ Wt1,
                                                  int K, int N, int ldw) {
    const float* W = blockIdx.z ? W1 : W0;
    u16* Wt = blockIdx.z ? Wt1 : Wt0;
    __shared__ float tile[32][33];
    const int k0 = blockIdx.x * 32, n0 = blockIdx.y * 32;
    const int tx = threadIdx.x & 31, ty = threadIdx.x >> 5;
    const int csrc = GLUPERM ? ((tx & 1) * 1024 + (n0 >> 1) + (tx >> 1)) : (n0 + tx);
    for (int i = 0; i < 4; ++i)
        tile[ty + i * 8][tx] = W[(size_t)(k0 + ty + i * 8) * ldw + csrc];
    __syncthreads();
    for (int i = 0; i < 4; ++i)
        Wt[(size_t)(n0 + ty + i * 8) * K + k0 + tx] = f2bf(tile[tx][ty + i * 8]);
}

// ================= GEMM 256xBN, 8 waves, counted-vmcnt pipeline =============
// PROVEN R5 structure (passed, W1=95us). BM=256, BN=WN*64, BK=64, 512 thr.
// Stage K-step s+2 into the buffer whose reads just drained (barrier#1);
// vmcnt(LOADS) waits only s+1's loads (s+2's stay in flight across barrier#2).
// EPI: 0 bf16(+bias) ; 1 silu bf16(+bias) ; 3 f32 res+rscale*(acc+bias) ;
//      4 GLU pairs -> bf16 [M][N/2] ; 5 rope(all cols)*rscale -> bf16
template <int EPI, int WM>
__global__ __launch_bounds__(512, 2) void gemm256(const u16* __restrict__ A,
                                                  const u16* __restrict__ Bt,
                                                  const float* __restrict__ bias,
                                                  const float* __restrict__ res,
                                                  float rscale,
                                                  void* __restrict__ outp,
                                                  const float* __restrict__ CT,
                                                  const float* __restrict__ ST,
                                                  int M, int N, int K, int nbx) {
    constexpr int WN = 8 / WM;
    constexpr int BN = WN * 64;
    constexpr int FM = 16 / WM;               // A frags per wave (m)
    __shared__ u16 sA[2][256 * 64];
    __shared__ u16 sB[2][BN * 64];
    const int tid = threadIdx.x, lane = tid & 63, w = tid >> 6;
    const int wm = w / WN, wn = w % WN;
    const int fr = lane & 15, fq = lane >> 4, frx = fr & 7;
    const int cpx = gridDim.x >> 3;           // bijective XCD swizzle (grid%8==0)
    const int lid = (blockIdx.x & 7) * cpx + (blockIdx.x >> 3);
    const int bn0 = (lid % nbx) * BN;
    const int bm0 = (lid / nbx) * 256;

    f32x4 acc[FM][4] = {};

    const int lrow = lane >> 3;
    const int lslot = (lane & 7) ^ (lrow & 7);            // pre-swizzled source
    const u16* ga = A  + (size_t)(bm0 + w * 8 + lrow) * K + lslot * 8;
    const u16* gb = Bt + (size_t)(bn0 + w * 8 + lrow) * K + lslot * 8;
    const size_t rs64 = (size_t)64 * K;
    const int lbase = w * 8 * 64;

    const int NK = K >> 6;

#define STAGE(bufi, kt)                                                        \
    {                                                                          \
        _Pragma("unroll")                                                      \
        for (int i = 0; i < 4; ++i)                                            \
            gload16(ga + (kt) + i * rs64, &sA[bufi][lbase + i * 4096]);        \
        _Pragma("unroll")                                                      \
        for (int i = 0; i < BN / 64; ++i)                                      \
            gload16(gb + (kt) + i * rs64, &sB[bufi][lbase + i * 4096]);        \
    }

    // prologue: K-steps 0 and 1 in flight; wait for K0 only
    STAGE(0, 0)
    STAGE(1, 64)
    if constexpr (WM == 2) asm volatile("s_waitcnt vmcnt(8)" ::: "memory");
    else                   asm volatile("s_waitcnt vmcnt(6)" ::: "memory");
    __builtin_amdgcn_sched_barrier(0);
    __builtin_amdgcn_s_barrier();

    const int arow0 = wm * (256 / WM) + fr;
    const int brow0 = wn * 64 + fr;

    for (int s = 0; s < NK; ++s) {
        const int buf = s & 1;
        bf16x8 afr[FM], bfr[4];
        // ---- phase 1: kslot 0 ----
#pragma unroll
        for (int mi = 0; mi < FM; ++mi)
            afr[mi] = *(const bf16x8*)(&sA[buf][(arow0 + mi * 16) * 64 + ((fq ^ frx) << 3)]);
#pragma unroll
        for (int ni = 0; ni < 4; ++ni)
            bfr[ni] = *(const bf16x8*)(&sB[buf][(brow0 + ni * 16) * 64 + ((fq ^ frx) << 3)]);
        asm volatile("s_waitcnt lgkmcnt(0)" ::: "memory");
        __builtin_amdgcn_sched_barrier(0);
        __builtin_amdgcn_s_setprio(1);
#pragma unroll
        for (int mi = 0; mi < FM; ++mi)
#pragma unroll
            for (int ni = 0; ni < 4; ++ni)
                acc[mi][ni] = __builtin_amdgcn_mfma_f32_16x16x32_bf16(
                    bfr[ni], afr[mi], acc[mi][ni], 0, 0, 0);   // D[n][m]
        __builtin_amdgcn_s_setprio(0);
        // ---- phase 2: kslot 1 ----
#pragma unroll
        for (int mi = 0; mi < FM; ++mi)
            afr[mi] = *(const bf16x8*)(&sA[buf][(arow0 + mi * 16) * 64 + (((4 + fq) ^ frx) << 3)]);
#pragma unroll
        for (int ni = 0; ni < 4; ++ni)
            bfr[ni] = *(const bf16x8*)(&sB[buf][(brow0 + ni * 16) * 64 + (((4 + fq) ^ frx) << 3)]);
        asm volatile("s_waitcnt lgkmcnt(0)" ::: "memory");
        __builtin_amdgcn_sched_barrier(0);
        __builtin_amdgcn_s_barrier();          // all waves done reading buf
        if (s + 2 < NK) {
            STAGE(buf, (s + 2) << 6)           // overwrite drained buf
        }
        __builtin_amdgcn_sched_barrier(0);
        __builtin_amdgcn_s_setprio(1);
#pragma unroll
        for (int mi = 0; mi < FM; ++mi)
#pragma unroll
            for (int ni = 0; ni < 4; ++ni)
                acc[mi][ni] = __builtin_amdgcn_mfma_f32_16x16x32_bf16(
                    bfr[ni], afr[mi], acc[mi][ni], 0, 0, 0);
        __builtin_amdgcn_s_setprio(0);
        // wait for K-step s+1's loads (s+2's remain in flight)
        if (s + 2 < NK) {
            if constexpr (WM == 2) asm volatile("s_waitcnt vmcnt(8)" ::: "memory");
            else                   asm volatile("s_waitcnt vmcnt(6)" ::: "memory");
        } else {
            asm volatile("s_waitcnt vmcnt(0)" ::: "memory");
        }
        __builtin_amdgcn_sched_barrier(0);
        __builtin_amdgcn_s_barrier();          // next buf ready for phase-1 reads
    }

    // epilogue: lane holds rows m = bm0+wm*(256/WM)+mi*16+fr, cols n0..n0+3
#pragma unroll
    for (int mi = 0; mi < FM; ++mi) {
        const int m = bm0 + wm * (256 / WM) + mi * 16 + fr;
        if (EPI == 5) {
            const int tq = m & 1023;
            const int colbase = bn0 + wn * 64;
#pragma unroll
            for (int ni = 0; ni < 2; ++ni) {
                const int j0 = ni * 16 + fq * 4;           // in-head col (0..31)
                const f32x4 c = *(const f32x4*)(CT + tq * 32 + j0);
                const f32x4 sn = *(const f32x4*)(ST + tq * 32 + j0);
                union { uint2 u2; u16 hh[4]; } o1, o2;
#pragma unroll
                for (int r = 0; r < 4; ++r) {
                    const float x1 = acc[mi][ni][r];
                    const float x2 = acc[mi][ni + 2][r];
                    o1.hh[r] = f2bf((x1 * c[r] - x2 * sn[r]) * rscale);
                    o2.hh[r] = f2bf((x2 * c[r] + x1 * sn[r]) * rscale);
                }
                *(uint2*)((u16*)outp + (size_t)m * N + colbase + j0) = o1.u2;
                *(uint2*)((u16*)outp + (size_t)m * N + colbase + j0 + 32) = o2.u2;
            }
            continue;
        }
#pragma unroll
        for (int ni = 0; ni < 4; ++ni) {
            const int n0 = bn0 + wn * 64 + ni * 16 + fq * 4;
            if (EPI == 0 || EPI == 1) {
                union { uint2 u2; u16 hh[4]; } ok;
#pragma unroll
                for (int r = 0; r < 4; ++r) {
                    float v = acc[mi][ni][r] + (bias ? bias[n0 + r] : 0.f);
                    if (EPI == 1) v = v / (1.f + __expf(-v));
                    ok.hh[r] = f2bf(v);
                }
                *(uint2*)((u16*)outp + (size_t)m * N + n0) = ok.u2;
            } else if (EPI == 3) {
                const f32x4 rv = *(const f32x4*)(res + (size_t)m * N + n0);
                f32x4 v;
#pragma unroll
                for (int r = 0; r < 4; ++r)
                    v[r] = rv[r] + rscale * (acc[mi][ni][r] + (bias ? bias[n0 + r] : 0.f));
                *(f32x4*)((float*)outp + (size_t)m * N + n0) = v;
            } else if (EPI == 4) {             // GLU pairs (interleaved cols)
                float vv[4];
#pragma unroll
                for (int r = 0; r < 4; ++r) {
                    const int n = n0 + r;
                    vv[r] = acc[mi][ni][r] + bias[((n & 1) << 10) + (n >> 1)];
                }
                union { uint32_t u; u16 hh[2]; } ok;
                ok.hh[0] = f2bf(vv[0] / (1.f + __expf(-vv[1])));
                ok.hh[1] = f2bf(vv[2] / (1.f + __expf(-vv[3])));
                *(uint32_t*)((u16*)outp + (size_t)m * (N >> 1) + (n0 >> 1)) = ok.u;
            }
        }
    }
#undef STAGE
}

// ---------- GEMM 128x128 (small shapes: wkva, wkvb) ----------
// EPI: 2 = f32(+bias) ; 6 = rope(cols<256) else plain -> bf16
template <int EPI>
__global__ __launch_bounds__(256, 2) void gemm128p(const u16* __restrict__ A,
                                                   const u16* __restrict__ Bt,
                                                   const float* __restrict__ bias,
                                                   const float* __restrict__ res,
                                                   float rscale,
                                                   void* __restrict__ outp,
                                                   const float* __restrict__ CT,
                                                   const float* __restrict__ ST,
                                                   int M, int N, int K, int nbx) {
    __shared__ u16 sA[2][128 * 64];
    __shared__ u16 sB[2][128 * 64];
    const int tid = threadIdx.x, lane = tid & 63, w = tid >> 6;
    const int wm = w >> 1, wn = w & 1;
    const int fr = lane & 15, fq = lane >> 4, frx = fr & 7;
    const int cpx = gridDim.x >> 3;
    const int lid = (blockIdx.x & 7) * cpx + (blockIdx.x >> 3);
    const int bn0 = (lid % nbx) * 128;
    const int bm0 = (lid / nbx) * 128;

    f32x4 acc[4][4] = {};

    const int lrow = lane >> 3;
    const int lslot = (lane & 7) ^ lrow;
    const u16* ga0 = A  + (size_t)(bm0 + w * 8 + lrow) * K + lslot * 8;
    const u16* gb0 = Bt + (size_t)(bn0 + w * 8 + lrow) * K + lslot * 8;
    const size_t rstep32 = (size_t)32 * K;
    const int NK = K >> 6;

#define STAGE(bufi, kt)                                                         \
    {                                                                           \
        _Pragma("unroll")                                                       \
        for (int i = 0; i < 4; ++i) {                                           \
            gload16(ga0 + (kt) + i * rstep32, &sA[bufi][w * 512 + i * 2048]);   \
            gload16(gb0 + (kt) + i * rstep32, &sB[bufi][w * 512 + i * 2048]);   \
        }                                                                       \
    }

    STAGE(0, 0)
    STAGE(1, 64)
    asm volatile("s_waitcnt vmcnt(8)" ::: "memory");
    __builtin_amdgcn_sched_barrier(0);
    __builtin_amdgcn_s_barrier();

    for (int s = 0; s < NK; ++s) {
        const int buf = s & 1;
        bf16x8 afr[4], bfr[4], afr2[4], bfr2[4];
#pragma unroll
        for (int i = 0; i < 4; ++i) {
            afr[i] = *(const bf16x8*)(&sA[buf][(wm * 64 + i * 16 + fr) * 64 + ((fq ^ frx) << 3)]);
            bfr[i] = *(const bf16x8*)(&sB[buf][(wn * 64 + i * 16 + fr) * 64 + ((fq ^ frx) << 3)]);
        }
        asm volatile("s_waitcnt lgkmcnt(0)" ::: "memory");
        __builtin_amdgcn_sched_barrier(0);
        __builtin_amdgcn_s_setprio(1);
#pragma unroll
        for (int mi = 0; mi < 4; ++mi)
#pragma unroll
            for (int ni = 0; ni < 4; ++ni)
                acc[mi][ni] = __builtin_amdgcn_mfma_f32_16x16x32_bf16(
                    bfr[ni], afr[mi], acc[mi][ni], 0, 0, 0);
        __builtin_amdgcn_s_setprio(0);
#pragma unroll
        for (int i = 0; i < 4; ++i) {
            afr2[i] = *(const bf16x8*)(&sA[buf][(wm * 64 + i * 16 + fr) * 64 + (((4 + fq) ^ frx) << 3)]);
            bfr2[i] = *(const bf16x8*)(&sB[buf][(wn * 64 + i * 16 + fr) * 64 + (((4 + fq) ^ frx) << 3)]);
        }
        asm volatile("s_waitcnt lgkmcnt(0)" ::: "memory");
        __builtin_amdgcn_sched_barrier(0);
        __builtin_amdgcn_s_barrier();
        if (s + 2 < NK) STAGE(buf, (s + 2) << 6)
        __builtin_amdgcn_sched_barrier(0);
        __builtin_amdgcn_s_setprio(1);
#pragma unroll
        for (int mi = 0; mi < 4; ++mi)
#pragma unroll
            for (int ni = 0; ni < 4; ++ni)
                acc[mi][ni] = __builtin_amdgcn_mfma_f32_16x16x32_bf16(
                    bfr2[ni], afr2[mi], acc[mi][ni], 0, 0, 0);
        __builtin_amdgcn_s_setprio(0);
        if (s + 2 < NK) { asm volatile("s_waitcnt vmcnt(8)" ::: "memory"); }
        else            { asm volatile("s_waitcnt vmcnt(0)" ::: "memory"); }
        __builtin_amdgcn_sched_barrier(0);
        __builtin_amdgcn_s_barrier();
    }

#pragma unroll
    for (int mi = 0; mi < 4; ++mi) {
        const int m = bm0 + wm * 64 + mi * 16 + fr;
        if (EPI == 6) {
            const int tq = m & 1023;
            const int colbase = bn0 + wn * 64;
            if (colbase < 256) {
#pragma unroll
                for (int ni = 0; ni < 2; ++ni) {
                    const int j0 = ni * 16 + fq * 4;
                    const f32x4 c = *(const f32x4*)(CT + tq * 32 + j0);
                    const f32x4 sn = *(const f32x4*)(ST + tq * 32 + j0);
                    union { uint2 u2; u16 hh[4]; } o1, o2;
#pragma unroll
                    for (int r = 0; r < 4; ++r) {
                        const float x1 = acc[mi][ni][r];
                        const float x2 = acc[mi][ni + 2][r];
                        o1.hh[r] = f2bf(x1 * c[r] - x2 * sn[r]);
                        o2.hh[r] = f2bf(x2 * c[r] + x1 * sn[r]);
                    }
                    *(uint2*)((u16*)outp + (size_t)m * N + colbase + j0) = o1.u2;
                    *(uint2*)((u16*)outp + (size_t)m * N + colbase + j0 + 32) = o2.u2;
                }
            } else {
#pragma unroll
                for (int ni = 0; ni < 4; ++ni) {
                    const int n0 = colbase + ni * 16 + fq * 4;
                    union { uint2 u2; u16 hh[4]; } ok;
#pragma unroll
                    for (int r = 0; r < 4; ++r) ok.hh[r] = f2bf(acc[mi][ni][r]);
                    *(uint2*)((u16*)outp + (size_t)m * N + n0) = ok.u2;
                }
            }
            continue;
        }
#pragma unroll
        for (int ni = 0; ni < 4; ++ni) {
            const int n0 = bn0 + wn * 64 + ni * 16 + fq * 4;
            f32x4 v;
#pragma unroll
            for (int r = 0; r < 4; ++r)
                v[r] = acc[mi][ni][r] + (bias ? bias[n0 + r] : 0.f);
            *(f32x4*)((float*)outp + (size_t)m * N + n0) = v;
        }
    }
#undef STAGE
}

// ---------- RoPE tables ----------
__global__ __launch_bounds__(256) void rope_tables_kernel(float* __restrict__ ct,
                                                          float* __restrict__ st) {
    const int i = blockIdx.x * 256 + threadIdx.x;
    const int t = i >> 5, j = i & 31;
    const float inv = powf(10000.f, -(float)j / 32.f);
    const float f = (float)t * inv;
    ct[i] = cosf(f);
    st[i] = sinf(f);
}

// ---------- V transpose ----------
__global__ __launch_bounds__(256) void vtranspose_kernel(const u16* __restrict__ KV,
                                                         u16* __restrict__ Vt) {
    __shared__ u16 tile[32][33];
    const int t0 = blockIdx.x * 32, h0 = blockIdx.y * 32;
    const int bk = blockIdx.z;
    const int b = bk >> 2, kh = bk & 3;
    const int tx = threadIdx.x & 31, ty = threadIdx.x >> 5;
    for (int i = 0; i < 4; ++i)
        tile[ty + i * 8][tx] =
            KV[(size_t)(b * 1024 + t0 + ty + i * 8) * 512 + 256 + kh * 64 + h0 + tx];
    __syncthreads();
    for (int i = 0; i < 4; ++i)
        Vt[((size_t)bk * 64 + h0 + ty + i * 8) * 1024 + t0 + tx] = tile[tx][ty + i * 8];
}

// ---------- fused SDPA v3: LDS-staged K/V shared by the 4 GQA heads ----------
__global__ __launch_bounds__(256) void attn_kernel(const u16* __restrict__ Q,
                                                   const u16* __restrict__ KV,
                                                   const u16* __restrict__ Vt,
                                                   u16* __restrict__ O) {
    __shared__ __align__(16) u16 sK[2][64 * 64];
    __shared__ __align__(16) u16 sV[2][64 * 64];
    __shared__ __align__(16) u16 sP[4][16 * 64];
    const int tid = threadIdx.x, lane = tid & 63, w = tid >> 6;
    const int fr = lane & 15, fq = lane >> 4, frx = fr & 7;
    const int bk = blockIdx.x, b = bk >> 2, kh = bk & 3;
    const int h = kh * 4 + w;
    const int q0 = blockIdx.y * 16;
    const int qrow = b * 1024 + q0 + fr;

    const int srow = w * 16 + (lane >> 3);
    const int sslot = (lane & 7) ^ ((lane >> 3) & 7);
    const u16* gK = KV + (size_t)(b * 1024 + srow) * 512 + kh * 64 + sslot * 8;
    const u16* gV = Vt + (size_t)((b * 4 + kh) * 64 + srow) * 1024 + sslot * 8;
    u16* dK = (u16*)sK + w * 16 * 64;
    u16* dV = (u16*)sV + w * 16 * 64;

    bf16x8 qf[2];
    qf[0] = *(const bf16x8*)(Q + (size_t)qrow * 1024 + h * 64 + fq * 8);
    qf[1] = *(const bf16x8*)(Q + (size_t)qrow * 1024 + h * 64 + 32 + fq * 8);

    f32x4 oacc[4] = {};
    float mrun = -1e30f, lrun = 0.f;
    u16* sPw = sP[w];

    gload16(gK, dK);
    gload16(gK + (size_t)8 * 512, dK + 8 * 64);
    gload16(gV, dV);
    gload16(gV + (size_t)8 * 1024, dV + 8 * 64);
    __syncthreads();

    int cur = 0;
    for (int t = 0; t < 16; ++t) {
        const int kv0 = t * 64;
        if (t < 15) {
            const int kn = kv0 + 64;
            const int nx = (cur ^ 1) * 4096;
            gload16(gK + (size_t)kn * 512,       dK + nx);
            gload16(gK + (size_t)(kn + 8) * 512, dK + nx + 8 * 64);
            gload16(gV + kn,                     dV + nx);
            gload16(gV + kn + (size_t)8 * 1024,  dV + nx + 8 * 64);
        }
        const u16* sKc = (u16*)sK + cur * 4096;
        const u16* sVc = (u16*)sV + cur * 4096;
        f32x4 sacc[4] = {};
#pragma unroll
        for (int ks = 0; ks < 2; ++ks)
#pragma unroll
            for (int nb = 0; nb < 4; ++nb) {
                const bf16x8 kf = *(const bf16x8*)(
                    sKc + (nb * 16 + fr) * 64 + (((ks * 4 + fq) ^ frx) << 3));
                sacc[nb] = __builtin_amdgcn_mfma_f32_16x16x32_bf16(kf, qf[ks], sacc[nb], 0, 0, 0);
            }
        float pm;
        {
            float a0 = fmaxf(fmaxf(sacc[0][0], sacc[0][1]), fmaxf(sacc[0][2], sacc[0][3]));
            float a1 = fmaxf(fmaxf(sacc[1][0], sacc[1][1]), fmaxf(sacc[1][2], sacc[1][3]));
            float a2 = fmaxf(fmaxf(sacc[2][0], sacc[2][1]), fmaxf(sacc[2][2], sacc[2][3]));
            float a3 = fmaxf(fmaxf(sacc[3][0], sacc[3][1]), fmaxf(sacc[3][2], sacc[3][3]));
            pm = fmaxf(fmaxf(a0, a1), fmaxf(a2, a3));
        }
        pm = fmaxf(pm, __shfl_xor(pm, 16, 64));
        pm = fmaxf(pm, __shfl_xor(pm, 32, 64));
        if (!__all(pm <= mrun + 8.f)) {
            const float mn = fmaxf(mrun, pm);
            const float al = __expf(mrun - mn);
            mrun = mn;
            lrun *= al;
#pragma unroll
            for (int f = 0; f < 4; ++f) {
                f32x4 tt = oacc[f];
#pragma unroll
                for (int r = 0; r < 4; ++r) tt[r] *= al;
                oacc[f] = tt;
            }
        }
        float rs = 0.f;
#pragma unroll
        for (int nb = 0; nb < 4; ++nb) {
            union { uint2 u2; u16 hh[4]; } pk;
#pragma unroll
            for (int r = 0; r < 4; ++r) {
                const float p = __expf(sacc[nb][r] - mrun);
                rs += p;
                pk.hh[r] = f2bf(p);
            }
            const int slotl = nb * 2 + (fq >> 1);
            *(uint2*)(sPw + fr * 64 + (((slotl ^ frx) << 3) | ((fq & 1) << 2))) = pk.u2;
        }
        rs += __shfl_xor(rs, 16, 64);
        rs += __shfl_xor(rs, 32, 64);
        lrun += rs;
        asm volatile("s_waitcnt lgkmcnt(0)" ::: "memory");
        __builtin_amdgcn_sched_barrier(0);
#pragma unroll
        for (int ks2 = 0; ks2 < 2; ++ks2) {
            const bf16x8 pf = *(const bf16x8*)(
                sPw + fr * 64 + (((ks2 * 4 + fq) ^ frx) << 3));
#pragma unroll
            for (int f = 0; f < 4; ++f) {
                const bf16x8 vf = *(const bf16x8*)(
                    sVc + (f * 16 + fr) * 64 + (((ks2 * 4 + fq) ^ frx) << 3));
                oacc[f] = __builtin_amdgcn_mfma_f32_16x16x32_bf16(vf, pf, oacc[f], 0, 0, 0);
            }
        }
        __syncthreads();
        cur ^= 1;
    }

    const float linv = 1.f / lrun;
#pragma unroll
    for (int f = 0; f < 4; ++f) {
        union { uint2 u2; u16 hh[4]; } ok;
#pragma unroll
        for (int r = 0; r < 4; ++r) ok.hh[r] = f2bf(oacc[f][r] * linv);
        *(uint2*)(O + (size_t)qrow * 1024 + h * 64 + f * 16 + fq * 4) = ok.u2;
    }
}

// ---------- depthwise conv(K=31) + BN + SiLU ----------
__global__ __launch_bounds__(256) void dwconv_kernel(const u16* __restrict__ G,
                                                     const float* __restrict__ wt,
                                                     const float* __restrict__ wb,
                                                     const float* __restrict__ bg,
                                                     const float* __restrict__ bb,
                                                     const float* __restrict__ rm,
                                                     const float* __restrict__ rv,
                                                     u16* __restrict__ out) {
    __shared__ u16 sg[38 * 256];
    const int tid = threadIdx.x;
    const int d = blockIdx.x * 256 + tid;
    const int t0 = blockIdx.y * 8;
    const int b = blockIdx.z;
    const size_t base = (size_t)b * 1024 * 1024 + d;
    for (int i = 0; i < 38; ++i) {
        const int t = t0 - 15 + i;
        sg[i * 256 + tid] = (t >= 0 && t < 1024) ? G[base + (size_t)t * 1024] : (u16)0;
    }
    __syncthreads();
    float wreg[31];
#pragma unroll
    for (int k = 0; k < 31; ++k) wreg[k] = wt[d * 31 + k];
    const float scale = bg[d] * rsqrtf(rv[d] + 1e-5f);
    const float addv = wb[d] - rm[d];
#pragma unroll
    for (int j = 0; j < 8; ++j) {
        float acc = 0.f;
#pragma unroll
        for (int k = 0; k < 31; ++k) acc += bf2f(sg[(j + k) * 256 + tid]) * wreg[k];
        float y = (acc + addv) * scale + bb[d];
        y = y / (1.f + __expf(-y));
        out[base + (size_t)(t0 + j) * 1024] = f2bf(y);
    }
}

// =====================================================================
extern "C" void kernel_launch(void* const* d_in, const int* in_sizes, int n_in,
                              void* d_out, int out_size, void* d_ws, size_t ws_size,
                              hipStream_t stream) {
    (void)in_sizes; (void)n_in; (void)out_size;

    const float* x       = (const float*)d_in[0];
    const float* ff1_ng  = (const float*)d_in[1];
    const float* ff1_nb  = (const float*)d_in[2];
    const float* ff1_w1  = (const float*)d_in[3];
    const float* ff1_b1  = (const float*)d_in[4];
    const float* ff1_w2  = (const float*)d_in[5];
    const float* ff1_b2  = (const float*)d_in[6];
    const float* attn_ng = (const float*)d_in[7];
    const float* attn_nb = (const float*)d_in[8];
    const float* wq      = (const float*)d_in[9];
    const float* wkva    = (const float*)d_in[10];
    const float* kvn_g   = (const float*)d_in[11];
    const float* kvn_b   = (const float*)d_in[12];
    const float* wkvb    = (const float*)d_in[13];
    const float* wo      = (const float*)d_in[14];
    const float* conv_ng = (const float*)d_in[15];
    const float* conv_nb = (const float*)d_in[16];
    const float* pw1_w   = (const float*)d_in[17];
    const float* pw1_b   = (const float*)d_in[18];
    const float* dw_w    = (const float*)d_in[19];
    const float* dw_b    = (const float*)d_in[20];
    const float* bn_g    = (const float*)d_in[21];
    const float* bn_b    = (const float*)d_in[22];
    const float* bn_rm   = (const float*)d_in[23];
    const float* bn_rv   = (const float*)d_in[24];
    const float* pw2_w   = (const float*)d_in[25];
    const float* pw2_b   = (const float*)d_in[26];
    const float* ff2_ng  = (const float*)d_in[27];
    const float* ff2_nb  = (const float*)d_in[28];
    const float* ff2_w1  = (const float*)d_in[29];
    const float* ff2_b1  = (const float*)d_in[30];
    const float* ff2_w2  = (const float*)d_in[31];
    const float* ff2_b2  = (const float*)d_in[32];
    const float* fin_g   = (const float*)d_in[33];
    const float* fin_b   = (const float*)d_in[34];

    const int M = 8192;
    char* ws = (char*)d_ws;
    size_t off = 0;
    auto alloc = [&](size_t bytes) {
        size_t o = off;
        off += (bytes + 255) & ~(size_t)255;
        return o;
    };
    const size_t o_ff1w1 = alloc((size_t)4096 * 1024 * 2);
    const size_t o_ff1w2 = alloc((size_t)1024 * 4096 * 2);
    const size_t o_wq    = alloc((size_t)1024 * 1024 * 2);
    const size_t o_wkva  = alloc((size_t)256 * 1024 * 2);
    const size_t o_wkvb  = alloc((size_t)512 * 256 * 2);
    const size_t o_wo    = alloc((size_t)1024 * 1024 * 2);
    const size_t o_pw1   = alloc((size_t)2048 * 1024 * 2);
    const size_t o_pw2   = alloc((size_t)1024 * 1024 * 2);
    const size_t o_ff2w1 = alloc((size_t)4096 * 1024 * 2);
    const size_t o_ff2w2 = alloc((size_t)1024 * 4096 * 2);
    const size_t o_ctab  = alloc((size_t)1024 * 32 * 4);
    const size_t o_stab  = alloc((size_t)1024 * 32 * 4);
    const size_t o_xres  = alloc((size_t)M * 1024 * 4);
    const size_t o_ln    = alloc((size_t)M * 1024 * 2);
    const size_t o_bufa  = alloc((size_t)64 * 1024 * 1024);
    if (ws_size < off) return;

    u16* BUFA = (u16*)(ws + o_bufa);
    u16* Qb    = BUFA;
    u16* KVb   = (u16*)((char*)BUFA + (16u << 20));
    float* KVA = (float*)((char*)BUFA + (24u << 20));
    u16* LAT   = (u16*)((char*)BUFA + (32u << 20));
    u16* VT    = (u16*)((char*)BUFA + (36u << 20));
    u16* OB    = (u16*)((char*)BUFA + (40u << 20));
    u16* PW1G  = BUFA;
    u16* CONVO = (u16*)((char*)BUFA + (16u << 20));
    u16* HID   = BUFA;

    u16* WT_FF1W1 = (u16*)(ws + o_ff1w1);
    u16* WT_FF1W2 = (u16*)(ws + o_ff1w2);
    u16* WT_WQ    = (u16*)(ws + o_wq);
    u16* WT_WKVA  = (u16*)(ws + o_wkva);
    u16* WT_WKVB  = (u16*)(ws + o_wkvb);
    u16* WT_WO    = (u16*)(ws + o_wo);
    u16* WT_PW1   = (u16*)(ws + o_pw1);
    u16* WT_PW2   = (u16*)(ws + o_pw2);
    u16* WT_FF2W1 = (u16*)(ws + o_ff2w1);
    u16* WT_FF2W2 = (u16*)(ws + o_ff2w2);
    float* CT = (float*)(ws + o_ctab);
    float* ST = (float*)(ws + o_stab);
    float* XR = (float*)(ws + o_xres);
    u16* LNB  = (u16*)(ws + o_ln);

    // --- weight conversion (paired where shapes match) ---
    wconvert_t<0><<<dim3(32, 128, 2), 256, 0, stream>>>(ff1_w1, WT_FF1W1, ff2_w1, WT_FF2W1, 1024, 4096, 4096);
    wconvert_t<0><<<dim3(128, 32, 2), 256, 0, stream>>>(ff1_w2, WT_FF1W2, ff2_w2, WT_FF2W2, 4096, 1024, 1024);
    wconvert_t<0><<<dim3(32, 32, 2),  256, 0, stream>>>(wq, WT_WQ, wo, WT_WO, 1024, 1024, 1024);
    wconvert_t<0><<<dim3(32, 32, 1),  256, 0, stream>>>(pw2_w, WT_PW2, pw2_w, WT_PW2, 1024, 1024, 1024);
    wconvert_t<0><<<dim3(32, 8, 1),   256, 0, stream>>>(wkva, WT_WKVA, wkva, WT_WKVA, 1024, 256, 320);
    wconvert_t<0><<<dim3(8, 16, 1),   256, 0, stream>>>(wkvb, WT_WKVB, wkvb, WT_WKVB, 256, 512, 512);
    wconvert_t<1><<<dim3(32, 64, 1),  256, 0, stream>>>(pw1_w, WT_PW1, pw1_w, WT_PW1, 1024, 2048, 2048);
    rope_tables_kernel<<<128, 256, 0, stream>>>(CT, ST);

    // --- FFN1 (macaron half) ---
    ln_kernel<0><<<M, 256, 0, stream>>>(x, ff1_ng, ff1_nb, LNB, 1024);
    gemm256<1, 2><<<512, 512, 0, stream>>>(LNB, WT_FF1W1, ff1_b1, nullptr, 0.f, HID, nullptr, nullptr, M, 4096, 1024, 16);
    gemm256<3, 4><<<256, 512, 0, stream>>>(HID, WT_FF1W2, ff1_b2, x, 0.5f, XR, nullptr, nullptr, M, 1024, 4096, 8);

    // --- attention (RMLA); RoPE fused into wq / wkvb epilogues ---
    ln_kernel<0><<<M, 256, 0, stream>>>(XR, attn_ng, attn_nb, LNB, 1024);
    gemm256<5, 4><<<256, 512, 0, stream>>>(LNB, WT_WQ, nullptr, nullptr, 0.125f, Qb, CT, ST, M, 1024, 1024, 8);
    gemm128p<2><<<128, 256, 0, stream>>>(LNB, WT_WKVA, nullptr, nullptr, 0.f, KVA, nullptr, nullptr, M, 256, 1024, 2);
    ln_kernel<0><<<M, 256, 0, stream>>>(KVA, kvn_g, kvn_b, LAT, 256);
    gemm128p<6><<<256, 256, 0, stream>>>(LAT, WT_WKVB, nullptr, nullptr, 1.0f, KVb, CT, ST, M, 512, 256, 4);
    vtranspose_kernel<<<dim3(32, 2, 32), 256, 0, stream>>>(KVb, VT);
    attn_kernel<<<dim3(32, 64), 256, 0, stream>>>(Qb, KVb, VT, OB);
    gemm256<3, 4><<<256, 512, 0, stream>>>(OB, WT_WO, nullptr, XR, 1.f, XR, nullptr, nullptr, M, 1024, 1024, 8);

    // --- conv module (GLU fused into pw1 epilogue) ---
    ln_kernel<0><<<M, 256, 0, stream>>>(XR, conv_ng, conv_nb, LNB, 1024);
    gemm256<4, 2><<<256, 512, 0, stream>>>(LNB, WT_PW1, pw1_b, nullptr, 0.f, PW1G, nullptr, nullptr, M, 2048, 1024, 8);
    dwconv_kernel<<<dim3(4, 128, 8), 256, 0, stream>>>(PW1G, dw_w, dw_b, bn_g, bn_b, bn_rm, bn_rv, CONVO);
    gemm256<3, 4><<<256, 512, 0, stream>>>(CONVO, WT_PW2, pw2_b, XR, 1.f, XR, nullptr, nullptr, M, 1024, 1024, 8);

    // --- FFN2 (macaron half) ---
    ln_kernel<0><<<M, 256, 0, stream>>>(XR, ff2_ng, ff2_nb, LNB, 1024);
    gemm256<1, 2><<<512, 512, 0, stream>>>(LNB, WT_FF2W1, ff2_b1, nullptr, 0.f, HID, nullptr, nullptr, M, 4096, 1024, 16);
    gemm256<3, 4><<<256, 512, 0, stream>>>(HID, WT_FF2W2, ff2_b2, XR, 0.5f, XR, nullptr, nullptr, M, 1024, 4096, 8);

    // --- final LN -> d_out (fp32) ---
    ln_kernel<1><<<M, 256, 0, stream>>>(XR, fin_g, fin_b, d_out, 1024);
}

// Round 11
// 712.089 us; speedup vs baseline: 1.1013x; 1.0273x over previous
//
#include <hip/hip_runtime.h>
#include <stdint.h>

typedef unsigned short u16;
using bf16x8 = __attribute__((ext_vector_type(8))) __bf16;
using f32x4  = __attribute__((ext_vector_type(4))) float;

// ---------- helpers ----------
__device__ __forceinline__ u16 f2bf(float f) {
    uint32_t u = __float_as_uint(f);
    u += 0x7fffu + ((u >> 16) & 1u);          // round-to-nearest-even
    return (u16)(u >> 16);
}
__device__ __forceinline__ float bf2f(u16 u) {
    return __uint_as_float(((uint32_t)u) << 16);
}
__device__ __forceinline__ void gload16(const void* g, void* l) {
    __builtin_amdgcn_global_load_lds(
        (__attribute__((address_space(1))) void*)(uintptr_t)g,
        (__attribute__((address_space(3))) void*)(uintptr_t)l,
        16, 0, 0);
}

// ---------- LayerNorm: fp32 in -> bf16 (mode 0) or fp32 (mode 1) out ----------
// D==1024 fast path: float4 per thread (G13: 16B/lane).
template <int OUTF32>
__global__ __launch_bounds__(256) void ln_kernel(const float* __restrict__ in,
                                                 const float* __restrict__ g,
                                                 const float* __restrict__ b,
                                                 void* __restrict__ out, int D) {
    const int row = blockIdx.x;
    const int tid = threadIdx.x;
    const float* x = in + (size_t)row * D;
    __shared__ float r1[4], r2[4];
    const int w = tid >> 6;
    if (D == 1024) {
        const f32x4 v = *(const f32x4*)(x + tid * 4);
        float s1 = v[0] + v[1] + v[2] + v[3];
        float s2 = v[0] * v[0] + v[1] * v[1] + v[2] * v[2] + v[3] * v[3];
        for (int o = 1; o < 64; o <<= 1) {
            s1 += __shfl_xor(s1, o, 64);
            s2 += __shfl_xor(s2, o, 64);
        }
        if ((tid & 63) == 0) { r1[w] = s1; r2[w] = s2; }
        __syncthreads();
        s1 = r1[0] + r1[1] + r1[2] + r1[3];
        s2 = r2[0] + r2[1] + r2[2] + r2[3];
        const float mean = s1 * (1.f / 1024.f);
        const float var  = s2 * (1.f / 1024.f) - mean * mean;
        const float inv  = rsqrtf(var + 1e-5f);
        const f32x4 gg = *(const f32x4*)(g + tid * 4);
        const f32x4 bb = *(const f32x4*)(b + tid * 4);
        if (OUTF32) {
            f32x4 y;
#pragma unroll
            for (int r = 0; r < 4; ++r) y[r] = (v[r] - mean) * inv * gg[r] + bb[r];
            *(f32x4*)((float*)out + (size_t)row * 1024 + tid * 4) = y;
        } else {
            union { uint2 u2; u16 hh[4]; } ok;
#pragma unroll
            for (int r = 0; r < 4; ++r) ok.hh[r] = f2bf((v[r] - mean) * inv * gg[r] + bb[r]);
            *(uint2*)((u16*)out + (size_t)row * 1024 + tid * 4) = ok.u2;
        }
        return;
    }
    // generic path (D=256)
    const int nv = D >> 8;
    float v[4];
    float s1 = 0.f, s2 = 0.f;
    for (int i = 0; i < nv; ++i) {
        float t = x[tid + (i << 8)];
        v[i] = t; s1 += t; s2 += t * t;
    }
    for (int o = 1; o < 64; o <<= 1) {
        s1 += __shfl_xor(s1, o, 64);
        s2 += __shfl_xor(s2, o, 64);
    }
    if ((tid & 63) == 0) { r1[w] = s1; r2[w] = s2; }
    __syncthreads();
    s1 = r1[0] + r1[1] + r1[2] + r1[3];
    s2 = r2[0] + r2[1] + r2[2] + r2[3];
    const float mean = s1 / (float)D;
    const float var  = s2 / (float)D - mean * mean;
    const float inv  = rsqrtf(var + 1e-5f);
    for (int i = 0; i < nv; ++i) {
        int c = tid + (i << 8);
        float y = (v[i] - mean) * inv * g[c] + b[c];
        if (OUTF32) ((float*)out)[(size_t)row * D + c] = y;
        else        ((u16*)out)[(size_t)row * D + c] = f2bf(y);
    }
}

// ---------- weight transpose + fp32->bf16 convert (z selects one of 2 jobs) ----------
template <int GLUPERM>
__global__ __launch_bounds__(256) void wconvert_t(const float* __restrict__ W0,
                                                  u16* __restrict__ Wt0,
                                                  const float* __restrict__ W1,
                                                  u16* __restrict__ Wt1,
                                                  int K, int N, int ldw) {
    const float* W = blockIdx.z ? W1 : W0;
    u16* Wt = blockIdx.z ? Wt1 : Wt0;
    __shared__ float tile[32][33];
    const int k0 = blockIdx.x * 32, n0 = blockIdx.y * 32;
    const int tx = threadIdx.x & 31, ty = threadIdx.x >> 5;
    const int csrc = GLUPERM ? ((tx & 1) * 1024 + (n0 >> 1) + (tx >> 1)) : (n0 + tx);
    for (int i = 0; i < 4; ++i)
        tile[ty + i * 8][tx] = W[(size_t)(k0 + ty + i * 8) * ldw + csrc];
    __syncthreads();
    for (int i = 0; i < 4; ++i)
        Wt[(size_t)(n0 + ty + i * 8) * K + k0 + tx] = f2bf(tile[tx][ty + i * 8]);
}

// ====== GEMM 256x128, BK=32, 8 waves, 3-deep LDS, 2 blocks/CU ==============
// C[M,N] = A[M,K](bf16) * Bt[N,K](bf16)^T. One barrier per K-step.
// Ledger: iter s reads tile s from buf s%3 (completed at lgkm0, before the
// iter-s barrier). Stage at TOP of iter s targets buf (s+2)%3, which held
// tile s-1 -- all waves finished reading it before iter (s-1)'s barrier.
// vmcnt(3) at iter end leaves exactly tile (s+2)'s 3 loads in flight, so
// tile s+1 is landed before iter s+1's reads. Tail drains to 0.
// R10 BUG FIX: ring increment (buf+2)%3 was wrong for buf==1 (gave 2, not 0),
// staging over the live buffer every 3rd step. Now computed exactly.
// EPI: 0 bf16(+bias) ; 1 silu bf16(+bias) ; 3 f32 res+rscale*(acc+bias) ;
//      4 GLU pairs -> bf16 [M][N/2] ; 5 rope(all cols)*rscale -> bf16
template <int EPI>
__global__ __launch_bounds__(512, 4) void gemm32(const u16* __restrict__ A,
                                                 const u16* __restrict__ Bt,
                                                 const float* __restrict__ bias,
                                                 const float* __restrict__ res,
                                                 float rscale,
                                                 void* __restrict__ outp,
                                                 const float* __restrict__ CT,
                                                 const float* __restrict__ ST,
                                                 int M, int N, int K, int nbx) {
    __shared__ u16 sA[3][256 * 32];
    __shared__ u16 sB[3][128 * 32];
    const int tid = threadIdx.x, lane = tid & 63, w = tid >> 6;
    const int wm = w >> 1, wn = w & 1;        // 4x2 wave grid (m x n)
    const int fr = lane & 15, fq = lane >> 4;
    const int cpx = gridDim.x >> 3;           // bijective XCD swizzle (grid%8==0)
    const int lid = (blockIdx.x & 7) * cpx + (blockIdx.x >> 3);
    const int bn0 = (lid % nbx) * 128;
    const int bm0 = (lid / nbx) * 256;

    f32x4 acc[4][4] = {};

    // staging: lane covers row lr=lane>>2 of a 16-row unit, phys slot lane&3;
    // source slot inverse-swizzled: sg = (lane&3) ^ ((lane>>3)&3)
    const int lr = lane >> 2;
    const int sg = (lane & 3) ^ ((lane >> 3) & 3);
    const u16* ga = A  + (size_t)(bm0 + w * 16 + lr) * K + sg * 8;
    const u16* gb = Bt + (size_t)(bn0 + w * 16 + lr) * K + sg * 8;
    const size_t rs128 = (size_t)128 * K;
    const int lbase = w * 512;                // 16 rows x 32 elems

    const int NK = K >> 5;
    const int rdsl = (fq ^ ((fr >> 1) & 3)) << 3;   // swizzled read slot (elems)
    const int arow0 = wm * 64 + fr;
    const int brow0 = wn * 64 + fr;

#define STAGE(bufi, s)                                                   \
    {                                                                    \
        gload16(ga + ((s) << 5),         &sA[bufi][lbase]);              \
        gload16(ga + ((s) << 5) + rs128, &sA[bufi][lbase + 4096]);       \
        gload16(gb + ((s) << 5),         &sB[bufi][lbase]);              \
    }
#define SB() __builtin_amdgcn_sched_barrier(0)

    // prologue: tiles 0,1 in flight; wait tile 0 only (3 of 6 outstanding)
    STAGE(0, 0)
    STAGE(1, 1)
    asm volatile("s_waitcnt vmcnt(3)" ::: "memory");
    SB();
    __builtin_amdgcn_s_barrier();

    int buf = 0;
    for (int s = 0; s < NK; ++s) {
        // stage tile s+2 into buffer (s+2)%3 (held tile s-1; reads done)
        if (s + 2 < NK) {
            int bn = buf + 2;
            if (bn >= 3) bn -= 3;             // exact (s+2)%3: 0->2, 1->0, 2->1
            STAGE(bn, s + 2)
        }
        bf16x8 afr[4], bfr[4];
#pragma unroll
        for (int i = 0; i < 4; ++i) {
            afr[i] = *(const bf16x8*)(&sA[buf][(arow0 + i * 16) * 32 + rdsl]);
            bfr[i] = *(const bf16x8*)(&sB[buf][(brow0 + i * 16) * 32 + rdsl]);
        }
        asm volatile("s_waitcnt lgkmcnt(0)" ::: "memory");
        SB();
        __builtin_amdgcn_s_setprio(1);
#pragma unroll
        for (int mi = 0; mi < 4; ++mi)
#pragma unroll
            for (int ni = 0; ni < 4; ++ni)
                acc[mi][ni] = __builtin_amdgcn_mfma_f32_16x16x32_bf16(
                    bfr[ni], afr[mi], acc[mi][ni], 0, 0, 0);   // D[n][m]
        __builtin_amdgcn_s_setprio(0);
        // wait tile s+1 landed (tile s+2's 3 loads stay in flight)
        if (s + 2 < NK)      { asm volatile("s_waitcnt vmcnt(3)" ::: "memory"); }
        else if (s + 1 < NK) { asm volatile("s_waitcnt vmcnt(0)" ::: "memory"); }
        SB();
        __builtin_amdgcn_s_barrier();          // all waves done with tile s
        buf = (buf == 2) ? 0 : buf + 1;
    }

    // epilogue: lane holds rows m = bm0+wm*64+mi*16+fr, cols n0..n0+3
#pragma unroll
    for (int mi = 0; mi < 4; ++mi) {
        const int m = bm0 + wm * 64 + mi * 16 + fr;
        if (EPI == 5) {
            const int tq = m & 1023;
            const int colbase = bn0 + wn * 64;
#pragma unroll
            for (int ni = 0; ni < 2; ++ni) {
                const int j0 = ni * 16 + fq * 4;           // in-head col (0..31)
                const f32x4 c = *(const f32x4*)(CT + tq * 32 + j0);
                const f32x4 sn = *(const f32x4*)(ST + tq * 32 + j0);
                union { uint2 u2; u16 hh[4]; } o1, o2;
#pragma unroll
                for (int r = 0; r < 4; ++r) {
                    const float x1 = acc[mi][ni][r];
                    const float x2 = acc[mi][ni + 2][r];
                    o1.hh[r] = f2bf((x1 * c[r] - x2 * sn[r]) * rscale);
                    o2.hh[r] = f2bf((x2 * c[r] + x1 * sn[r]) * rscale);
                }
                *(uint2*)((u16*)outp + (size_t)m * N + colbase + j0) = o1.u2;
                *(uint2*)((u16*)outp + (size_t)m * N + colbase + j0 + 32) = o2.u2;
            }
            continue;
        }
#pragma unroll
        for (int ni = 0; ni < 4; ++ni) {
            const int n0 = bn0 + wn * 64 + ni * 16 + fq * 4;
            if (EPI == 0 || EPI == 1) {
                union { uint2 u2; u16 hh[4]; } ok;
#pragma unroll
                for (int r = 0; r < 4; ++r) {
                    float v = acc[mi][ni][r] + (bias ? bias[n0 + r] : 0.f);
                    if (EPI == 1) v = v / (1.f + __expf(-v));
                    ok.hh[r] = f2bf(v);
                }
                *(uint2*)((u16*)outp + (size_t)m * N + n0) = ok.u2;
            } else if (EPI == 3) {
                const f32x4 rv = *(const f32x4*)(res + (size_t)m * N + n0);
                f32x4 v;
#pragma unroll
                for (int r = 0; r < 4; ++r)
                    v[r] = rv[r] + rscale * (acc[mi][ni][r] + (bias ? bias[n0 + r] : 0.f));
                *(f32x4*)((float*)outp + (size_t)m * N + n0) = v;
            } else if (EPI == 4) {             // GLU pairs (interleaved cols)
                float vv[4];
#pragma unroll
                for (int r = 0; r < 4; ++r) {
                    const int n = n0 + r;
                    vv[r] = acc[mi][ni][r] + bias[((n & 1) << 10) + (n >> 1)];
                }
                union { uint32_t u; u16 hh[2]; } ok;
                ok.hh[0] = f2bf(vv[0] / (1.f + __expf(-vv[1])));
                ok.hh[1] = f2bf(vv[2] / (1.f + __expf(-vv[3])));
                *(uint32_t*)((u16*)outp + (size_t)m * (N >> 1) + (n0 >> 1)) = ok.u;
            }
        }
    }
#undef STAGE
#undef SB
}

// ---------- GEMM 128x128 (small shapes: wkva, wkvb) ----------
// EPI: 2 = f32(+bias) ; 6 = rope(cols<256) else plain -> bf16
template <int EPI>
__global__ __launch_bounds__(256, 2) void gemm128p(const u16* __restrict__ A,
                                                   const u16* __restrict__ Bt,
                                                   const float* __restrict__ bias,
                                                   const float* __restrict__ res,
                                                   float rscale,
                                                   void* __restrict__ outp,
                                                   const float* __restrict__ CT,
                                                   const float* __restrict__ ST,
                                                   int M, int N, int K, int nbx) {
    __shared__ u16 sA[2][128 * 64];
    __shared__ u16 sB[2][128 * 64];
    const int tid = threadIdx.x, lane = tid & 63, w = tid >> 6;
    const int wm = w >> 1, wn = w & 1;
    const int fr = lane & 15, fq = lane >> 4, frx = fr & 7;
    const int cpx = gridDim.x >> 3;
    const int lid = (blockIdx.x & 7) * cpx + (blockIdx.x >> 3);
    const int bn0 = (lid % nbx) * 128;
    const int bm0 = (lid / nbx) * 128;

    f32x4 acc[4][4] = {};

    const int lrow = lane >> 3;
    const int lslot = (lane & 7) ^ lrow;
    const u16* ga0 = A  + (size_t)(bm0 + w * 8 + lrow) * K + lslot * 8;
    const u16* gb0 = Bt + (size_t)(bn0 + w * 8 + lrow) * K + lslot * 8;
    const size_t rstep32 = (size_t)32 * K;
    const int NK = K >> 6;

#define STAGE(bufi, kt)                                                         \
    {                                                                           \
        _Pragma("unroll")                                                       \
        for (int i = 0; i < 4; ++i) {                                           \
            gload16(ga0 + (kt) + i * rstep32, &sA[bufi][w * 512 + i * 2048]);   \
            gload16(gb0 + (kt) + i * rstep32, &sB[bufi][w * 512 + i * 2048]);   \
        }                                                                       \
    }

    STAGE(0, 0)
    STAGE(1, 64)
    asm volatile("s_waitcnt vmcnt(8)" ::: "memory");
    __builtin_amdgcn_sched_barrier(0);
    __builtin_amdgcn_s_barrier();

    for (int s = 0; s < NK; ++s) {
        const int buf = s & 1;
        bf16x8 afr[4], bfr[4], afr2[4], bfr2[4];
#pragma unroll
        for (int i = 0; i < 4; ++i) {
            afr[i] = *(const bf16x8*)(&sA[buf][(wm * 64 + i * 16 + fr) * 64 + ((fq ^ frx) << 3)]);
            bfr[i] = *(const bf16x8*)(&sB[buf][(wn * 64 + i * 16 + fr) * 64 + ((fq ^ frx) << 3)]);
        }
        asm volatile("s_waitcnt lgkmcnt(0)" ::: "memory");
        __builtin_amdgcn_sched_barrier(0);
        __builtin_amdgcn_s_setprio(1);
#pragma unroll
        for (int mi = 0; mi < 4; ++mi)
#pragma unroll
            for (int ni = 0; ni < 4; ++ni)
                acc[mi][ni] = __builtin_amdgcn_mfma_f32_16x16x32_bf16(
                    bfr[ni], afr[mi], acc[mi][ni], 0, 0, 0);
        __builtin_amdgcn_s_setprio(0);
#pragma unroll
        for (int i = 0; i < 4; ++i) {
            afr2[i] = *(const bf16x8*)(&sA[buf][(wm * 64 + i * 16 + fr) * 64 + (((4 + fq) ^ frx) << 3)]);
            bfr2[i] = *(const bf16x8*)(&sB[buf][(wn * 64 + i * 16 + fr) * 64 + (((4 + fq) ^ frx) << 3)]);
        }
        asm volatile("s_waitcnt lgkmcnt(0)" ::: "memory");
        __builtin_amdgcn_sched_barrier(0);
        __builtin_amdgcn_s_barrier();
        if (s + 2 < NK) STAGE(buf, (s + 2) << 6)
        __builtin_amdgcn_sched_barrier(0);
        __builtin_amdgcn_s_setprio(1);
#pragma unroll
        for (int mi = 0; mi < 4; ++mi)
#pragma unroll
            for (int ni = 0; ni < 4; ++ni)
                acc[mi][ni] = __builtin_amdgcn_mfma_f32_16x16x32_bf16(
                    bfr2[ni], afr2[mi], acc[mi][ni], 0, 0, 0);
        __builtin_amdgcn_s_setprio(0);
        if (s + 2 < NK) { asm volatile("s_waitcnt vmcnt(8)" ::: "memory"); }
        else            { asm volatile("s_waitcnt vmcnt(0)" ::: "memory"); }
        __builtin_amdgcn_sched_barrier(0);
        __builtin_amdgcn_s_barrier();
    }

#pragma unroll
    for (int mi = 0; mi < 4; ++mi) {
        const int m = bm0 + wm * 64 + mi * 16 + fr;
        if (EPI == 6) {
            const int tq = m & 1023;
            const int colbase = bn0 + wn * 64;
            if (colbase < 256) {
#pragma unroll
                for (int ni = 0; ni < 2; ++ni) {
                    const int j0 = ni * 16 + fq * 4;
                    const f32x4 c = *(const f32x4*)(CT + tq * 32 + j0);
                    const f32x4 sn = *(const f32x4*)(ST + tq * 32 + j0);
                    union { uint2 u2; u16 hh[4]; } o1, o2;
#pragma unroll
                    for (int r = 0; r < 4; ++r) {
                        const float x1 = acc[mi][ni][r];
                        const float x2 = acc[mi][ni + 2][r];
                        o1.hh[r] = f2bf(x1 * c[r] - x2 * sn[r]);
                        o2.hh[r] = f2bf(x2 * c[r] + x1 * sn[r]);
                    }
                    *(uint2*)((u16*)outp + (size_t)m * N + colbase + j0) = o1.u2;
                    *(uint2*)((u16*)outp + (size_t)m * N + colbase + j0 + 32) = o2.u2;
                }
            } else {
#pragma unroll
                for (int ni = 0; ni < 4; ++ni) {
                    const int n0 = colbase + ni * 16 + fq * 4;
                    union { uint2 u2; u16 hh[4]; } ok;
#pragma unroll
                    for (int r = 0; r < 4; ++r) ok.hh[r] = f2bf(acc[mi][ni][r]);
                    *(uint2*)((u16*)outp + (size_t)m * N + n0) = ok.u2;
                }
            }
            continue;
        }
#pragma unroll
        for (int ni = 0; ni < 4; ++ni) {
            const int n0 = bn0 + wn * 64 + ni * 16 + fq * 4;
            f32x4 v;
#pragma unroll
            for (int r = 0; r < 4; ++r)
                v[r] = acc[mi][ni][r] + (bias ? bias[n0 + r] : 0.f);
            *(f32x4*)((float*)outp + (size_t)m * N + n0) = v;
        }
    }
#undef STAGE
}

// ---------- RoPE tables ----------
__global__ __launch_bounds__(256) void rope_tables_kernel(float* __restrict__ ct,
                                                          float* __restrict__ st) {
    const int i = blockIdx.x * 256 + threadIdx.x;
    const int t = i >> 5, j = i & 31;
    const float inv = powf(10000.f, -(float)j / 32.f);
    const float f = (float)t * inv;
    ct[i] = cosf(f);
    st[i] = sinf(f);
}

// ---------- V transpose ----------
__global__ __launch_bounds__(256) void vtranspose_kernel(const u16* __restrict__ KV,
                                                         u16* __restrict__ Vt) {
    __shared__ u16 tile[32][33];
    const int t0 = blockIdx.x * 32, h0 = blockIdx.y * 32;
    const int bk = blockIdx.z;
    const int b = bk >> 2, kh = bk & 3;
    const int tx = threadIdx.x & 31, ty = threadIdx.x >> 5;
    for (int i = 0; i < 4; ++i)
        tile[ty + i * 8][tx] =
            KV[(size_t)(b * 1024 + t0 + ty + i * 8) * 512 + 256 + kh * 64 + h0 + tx];
    __syncthreads();
    for (int i = 0; i < 4; ++i)
        Vt[((size_t)bk * 64 + h0 + ty + i * 8) * 1024 + t0 + tx] = tile[tx][ty + i * 8];
}

// ---------- fused SDPA v3: LDS-staged K/V shared by the 4 GQA heads ----------
__global__ __launch_bounds__(256) void attn_kernel(const u16* __restrict__ Q,
                                                   const u16* __restrict__ KV,
                                                   const u16* __restrict__ Vt,
                                                   u16* __restrict__ O) {
    __shared__ __align__(16) u16 sK[2][64 * 64];
    __shared__ __align__(16) u16 sV[2][64 * 64];
    __shared__ __align__(16) u16 sP[4][16 * 64];
    const int tid = threadIdx.x, lane = tid & 63, w = tid >> 6;
    const int fr = lane & 15, fq = lane >> 4, frx = fr & 7;
    const int bk = blockIdx.x, b = bk >> 2, kh = bk & 3;
    const int h = kh * 4 + w;
    const int q0 = blockIdx.y * 16;
    const int qrow = b * 1024 + q0 + fr;

    const int srow = w * 16 + (lane >> 3);
    const int sslot = (lane & 7) ^ ((lane >> 3) & 7);
    const u16* gK = KV + (size_t)(b * 1024 + srow) * 512 + kh * 64 + sslot * 8;
    const u16* gV = Vt + (size_t)((b * 4 + kh) * 64 + srow) * 1024 + sslot * 8;
    u16* dK = (u16*)sK + w * 16 * 64;
    u16* dV = (u16*)sV + w * 16 * 64;

    bf16x8 qf[2];
    qf[0] = *(const bf16x8*)(Q + (size_t)qrow * 1024 + h * 64 + fq * 8);
    qf[1] = *(const bf16x8*)(Q + (size_t)qrow * 1024 + h * 64 + 32 + fq * 8);

    f32x4 oacc[4] = {};
    float mrun = -1e30f, lrun = 0.f;
    u16* sPw = sP[w];

    gload16(gK, dK);
    gload16(gK + (size_t)8 * 512, dK + 8 * 64);
    gload16(gV, dV);
    gload16(gV + (size_t)8 * 1024, dV + 8 * 64);
    __syncthreads();

    int cur = 0;
    for (int t = 0; t < 16; ++t) {
        const int kv0 = t * 64;
        if (t < 15) {
            const int kn = kv0 + 64;
            const int nx = (cur ^ 1) * 4096;
            gload16(gK + (size_t)kn * 512,       dK + nx);
            gload16(gK + (size_t)(kn + 8) * 512, dK + nx + 8 * 64);
            gload16(gV + kn,                     dV + nx);
            gload16(gV + kn + (size_t)8 * 1024,  dV + nx + 8 * 64);
        }
        const u16* sKc = (u16*)sK + cur * 4096;
        const u16* sVc = (u16*)sV + cur * 4096;
        f32x4 sacc[4] = {};
#pragma unroll
        for (int ks = 0; ks < 2; ++ks)
#pragma unroll
            for (int nb = 0; nb < 4; ++nb) {
                const bf16x8 kf = *(const bf16x8*)(
                    sKc + (nb * 16 + fr) * 64 + (((ks * 4 + fq) ^ frx) << 3));
                sacc[nb] = __builtin_amdgcn_mfma_f32_16x16x32_bf16(kf, qf[ks], sacc[nb], 0, 0, 0);
            }
        float pm;
        {
            float a0 = fmaxf(fmaxf(sacc[0][0], sacc[0][1]), fmaxf(sacc[0][2], sacc[0][3]));
            float a1 = fmaxf(fmaxf(sacc[1][0], sacc[1][1]), fmaxf(sacc[1][2], sacc[1][3]));
            float a2 = fmaxf(fmaxf(sacc[2][0], sacc[2][1]), fmaxf(sacc[2][2], sacc[2][3]));
            float a3 = fmaxf(fmaxf(sacc[3][0], sacc[3][1]), fmaxf(sacc[3][2], sacc[3][3]));
            pm = fmaxf(fmaxf(a0, a1), fmaxf(a2, a3));
        }
        pm = fmaxf(pm, __shfl_xor(pm, 16, 64));
        pm = fmaxf(pm, __shfl_xor(pm, 32, 64));
        if (!__all(pm <= mrun + 8.f)) {
            const float mn = fmaxf(mrun, pm);
            const float al = __expf(mrun - mn);
            mrun = mn;
            lrun *= al;
#pragma unroll
            for (int f = 0; f < 4; ++f) {
                f32x4 tt = oacc[f];
#pragma unroll
                for (int r = 0; r < 4; ++r) tt[r] *= al;
                oacc[f] = tt;
            }
        }
        float rs = 0.f;
#pragma unroll
        for (int nb = 0; nb < 4; ++nb) {
            union { uint2 u2; u16 hh[4]; } pk;
#pragma unroll
            for (int r = 0; r < 4; ++r) {
                const float p = __expf(sacc[nb][r] - mrun);
                rs += p;
                pk.hh[r] = f2bf(p);
            }
            const int slotl = nb * 2 + (fq >> 1);
            *(uint2*)(sPw + fr * 64 + (((slotl ^ frx) << 3) | ((fq & 1) << 2))) = pk.u2;
        }
        rs += __shfl_xor(rs, 16, 64);
        rs += __shfl_xor(rs, 32, 64);
        lrun += rs;
        asm volatile("s_waitcnt lgkmcnt(0)" ::: "memory");
        __builtin_amdgcn_sched_barrier(0);
#pragma unroll
        for (int ks2 = 0; ks2 < 2; ++ks2) {
            const bf16x8 pf = *(const bf16x8*)(
                sPw + fr * 64 + (((ks2 * 4 + fq) ^ frx) << 3));
#pragma unroll
            for (int f = 0; f < 4; ++f) {
                const bf16x8 vf = *(const bf16x8*)(
                    sVc + (f * 16 + fr) * 64 + (((ks2 * 4 + fq) ^ frx) << 3));
                oacc[f] = __builtin_amdgcn_mfma_f32_16x16x32_bf16(vf, pf, oacc[f], 0, 0, 0);
            }
        }
        __syncthreads();
        cur ^= 1;
    }

    const float linv = 1.f / lrun;
#pragma unroll
    for (int f = 0; f < 4; ++f) {
        union { uint2 u2; u16 hh[4]; } ok;
#pragma unroll
        for (int r = 0; r < 4; ++r) ok.hh[r] = f2bf(oacc[f][r] * linv);
        *(uint2*)(O + (size_t)qrow * 1024 + h * 64 + f * 16 + fq * 4) = ok.u2;
    }
}

// ---------- depthwise conv(K=31) + BN + SiLU ----------
__global__ __launch_bounds__(256) void dwconv_kernel(const u16* __restrict__ G,
                                                     const float* __restrict__ wt,
                                                     const float* __restrict__ wb,
                                                     const float* __restrict__ bg,
                                                     const float* __restrict__ bb,
                                                     const float* __restrict__ rm,
                                                     const float* __restrict__ rv,
                                                     u16* __restrict__ out) {
    __shared__ u16 sg[38 * 256];
    const int tid = threadIdx.x;
    const int d = blockIdx.x * 256 + tid;
    const int t0 = blockIdx.y * 8;
    const int b = blockIdx.z;
    const size_t base = (size_t)b * 1024 * 1024 + d;
    for (int i = 0; i < 38; ++i) {
        const int t = t0 - 15 + i;
        sg[i * 256 + tid] = (t >= 0 && t < 1024) ? G[base + (size_t)t * 1024] : (u16)0;
    }
    __syncthreads();
    float wreg[31];
#pragma unroll
    for (int k = 0; k < 31; ++k) wreg[k] = wt[d * 31 + k];
    const float scale = bg[d] * rsqrtf(rv[d] + 1e-5f);
    const float addv = wb[d] - rm[d];
#pragma unroll
    for (int j = 0; j < 8; ++j) {
        float acc = 0.f;
#pragma unroll
        for (int k = 0; k < 31; ++k) acc += bf2f(sg[(j + k) * 256 + tid]) * wreg[k];
        float y = (acc + addv) * scale + bb[d];
        y = y / (1.f + __expf(-y));
        out[base + (size_t)(t0 + j) * 1024] = f2bf(y);
    }
}

// =====================================================================
extern "C" void kernel_launch(void* const* d_in, const int* in_sizes, int n_in,
                              void* d_out, int out_size, void* d_ws, size_t ws_size,
                              hipStream_t stream) {
    (void)in_sizes; (void)n_in; (void)out_size;

    const float* x       = (const float*)d_in[0];
    const float* ff1_ng  = (const float*)d_in[1];
    const float* ff1_nb  = (const float*)d_in[2];
    const float* ff1_w1  = (const float*)d_in[3];
    const float* ff1_b1  = (const float*)d_in[4];
    const float* ff1_w2  = (const float*)d_in[5];
    const float* ff1_b2  = (const float*)d_in[6];
    const float* attn_ng = (const float*)d_in[7];
    const float* attn_nb = (const float*)d_in[8];
    const float* wq      = (const float*)d_in[9];
    const float* wkva    = (const float*)d_in[10];
    const float* kvn_g   = (const float*)d_in[11];
    const float* kvn_b   = (const float*)d_in[12];
    const float* wkvb    = (const float*)d_in[13];
    const float* wo      = (const float*)d_in[14];
    const float* conv_ng = (const float*)d_in[15];
    const float* conv_nb = (const float*)d_in[16];
    const float* pw1_w   = (const float*)d_in[17];
    const float* pw1_b   = (const float*)d_in[18];
    const float* dw_w    = (const float*)d_in[19];
    const float* dw_b    = (const float*)d_in[20];
    const float* bn_g    = (const float*)d_in[21];
    const float* bn_b    = (const float*)d_in[22];
    const float* bn_rm   = (const float*)d_in[23];
    const float* bn_rv   = (const float*)d_in[24];
    const float* pw2_w   = (const float*)d_in[25];
    const float* pw2_b   = (const float*)d_in[26];
    const float* ff2_ng  = (const float*)d_in[27];
    const float* ff2_nb  = (const float*)d_in[28];
    const float* ff2_w1  = (const float*)d_in[29];
    const float* ff2_b1  = (const float*)d_in[30];
    const float* ff2_w2  = (const float*)d_in[31];
    const float* ff2_b2  = (const float*)d_in[32];
    const float* fin_g   = (const float*)d_in[33];
    const float* fin_b   = (const float*)d_in[34];

    const int M = 8192;
    char* ws = (char*)d_ws;
    size_t off = 0;
    auto alloc = [&](size_t bytes) {
        size_t o = off;
        off += (bytes + 255) & ~(size_t)255;
        return o;
    };
    const size_t o_ff1w1 = alloc((size_t)4096 * 1024 * 2);
    const size_t o_ff1w2 = alloc((size_t)1024 * 4096 * 2);
    const size_t o_wq    = alloc((size_t)1024 * 1024 * 2);
    const size_t o_wkva  = alloc((size_t)256 * 1024 * 2);
    const size_t o_wkvb  = alloc((size_t)512 * 256 * 2);
    const size_t o_wo    = alloc((size_t)1024 * 1024 * 2);
    const size_t o_pw1   = alloc((size_t)2048 * 1024 * 2);
    const size_t o_pw2   = alloc((size_t)1024 * 1024 * 2);
    const size_t o_ff2w1 = alloc((size_t)4096 * 1024 * 2);
    const size_t o_ff2w2 = alloc((size_t)1024 * 4096 * 2);
    const size_t o_ctab  = alloc((size_t)1024 * 32 * 4);
    const size_t o_stab  = alloc((size_t)1024 * 32 * 4);
    const size_t o_xres  = alloc((size_t)M * 1024 * 4);
    const size_t o_ln    = alloc((size_t)M * 1024 * 2);
    const size_t o_bufa  = alloc((size_t)64 * 1024 * 1024);
    if (ws_size < off) return;

    u16* BUFA = (u16*)(ws + o_bufa);
    u16* Qb    = BUFA;
    u16* KVb   = (u16*)((char*)BUFA + (16u << 20));
    float* KVA = (float*)((char*)BUFA + (24u << 20));
    u16* LAT   = (u16*)((char*)BUFA + (32u << 20));
    u16* VT    = (u16*)((char*)BUFA + (36u << 20));
    u16* OB    = (u16*)((char*)BUFA + (40u << 20));
    u16* PW1G  = BUFA;
    u16* CONVO = (u16*)((char*)BUFA + (16u << 20));
    u16* HID   = BUFA;

    u16* WT_FF1W1 = (u16*)(ws + o_ff1w1);
    u16* WT_FF1W2 = (u16*)(ws + o_ff1w2);
    u16* WT_WQ    = (u16*)(ws + o_wq);
    u16* WT_WKVA  = (u16*)(ws + o_wkva);
    u16* WT_WKVB  = (u16*)(ws + o_wkvb);
    u16* WT_WO    = (u16*)(ws + o_wo);
    u16* WT_PW1   = (u16*)(ws + o_pw1);
    u16* WT_PW2   = (u16*)(ws + o_pw2);
    u16* WT_FF2W1 = (u16*)(ws + o_ff2w1);
    u16* WT_FF2W2 = (u16*)(ws + o_ff2w2);
    float* CT = (float*)(ws + o_ctab);
    float* ST = (float*)(ws + o_stab);
    float* XR = (float*)(ws + o_xres);
    u16* LNB  = (u16*)(ws + o_ln);

    // --- weight conversion (paired where shapes match) ---
    wconvert_t<0><<<dim3(32, 128, 2), 256, 0, stream>>>(ff1_w1, WT_FF1W1, ff2_w1, WT_FF2W1, 1024, 4096, 4096);
    wconvert_t<0><<<dim3(128, 32, 2), 256, 0, stream>>>(ff1_w2, WT_FF1W2, ff2_w2, WT_FF2W2, 4096, 1024, 1024);
    wconvert_t<0><<<dim3(32, 32, 2),  256, 0, stream>>>(wq, WT_WQ, wo, WT_WO, 1024, 1024, 1024);
    wconvert_t<0><<<dim3(32, 32, 1),  256, 0, stream>>>(pw2_w, WT_PW2, pw2_w, WT_PW2, 1024, 1024, 1024);
    wconvert_t<0><<<dim3(32, 8, 1),   256, 0, stream>>>(wkva, WT_WKVA, wkva, WT_WKVA, 1024, 256, 320);
    wconvert_t<0><<<dim3(8, 16, 1),   256, 0, stream>>>(wkvb, WT_WKVB, wkvb, WT_WKVB, 256, 512, 512);
    wconvert_t<1><<<dim3(32, 64, 1),  256, 0, stream>>>(pw1_w, WT_PW1, pw1_w, WT_PW1, 1024, 2048, 2048);
    rope_tables_kernel<<<128, 256, 0, stream>>>(CT, ST);

    // --- FFN1 (macaron half) ---
    ln_kernel<0><<<M, 256, 0, stream>>>(x, ff1_ng, ff1_nb, LNB, 1024);
    gemm32<1><<<1024, 512, 0, stream>>>(LNB, WT_FF1W1, ff1_b1, nullptr, 0.f, HID, nullptr, nullptr, M, 4096, 1024, 32);
    gemm32<3><<<256, 512, 0, stream>>>(HID, WT_FF1W2, ff1_b2, x, 0.5f, XR, nullptr, nullptr, M, 1024, 4096, 8);

    // --- attention (RMLA); RoPE fused into wq / wkvb epilogues ---
    ln_kernel<0><<<M, 256, 0, stream>>>(XR, attn_ng, attn_nb, LNB, 1024);
    gemm32<5><<<256, 512, 0, stream>>>(LNB, WT_WQ, nullptr, nullptr, 0.125f, Qb, CT, ST, M, 1024, 1024, 8);
    gemm128p<2><<<128, 256, 0, stream>>>(LNB, WT_WKVA, nullptr, nullptr, 0.f, KVA, nullptr, nullptr, M, 256, 1024, 2);
    ln_kernel<0><<<M, 256, 0, stream>>>(KVA, kvn_g, kvn_b, LAT, 256);
    gemm128p<6><<<256, 256, 0, stream>>>(LAT, WT_WKVB, nullptr, nullptr, 1.0f, KVb, CT, ST, M, 512, 256, 4);
    vtranspose_kernel<<<dim3(32, 2, 32), 256, 0, stream>>>(KVb, VT);
    attn_kernel<<<dim3(32, 64), 256, 0, stream>>>(Qb, KVb, VT, OB);
    gemm32<3><<<256, 512, 0, stream>>>(OB, WT_WO, nullptr, XR, 1.f, XR, nullptr, nullptr, M, 1024, 1024, 8);

    // --- conv module (GLU fused into pw1 epilogue) ---
    ln_kernel<0><<<M, 256, 0, stream>>>(XR, conv_ng, conv_nb, LNB, 1024);
    gemm32<4><<<512, 512, 0, stream>>>(LNB, WT_PW1, pw1_b, nullptr, 0.f, PW1G, nullptr, nullptr, M, 2048, 1024, 16);
    dwconv_kernel<<<dim3(4, 128, 8), 256, 0, stream>>>(PW1G, dw_w, dw_b, bn_g, bn_b, bn_rm, bn_rv, CONVO);
    gemm32<3><<<256, 512, 0, stream>>>(CONVO, WT_PW2, pw2_b, XR, 1.f, XR, nullptr, nullptr, M, 1024, 1024, 8);

    // --- FFN2 (macaron half) ---
    ln_kernel<0><<<M, 256, 0, stream>>>(XR, ff2_ng, ff2_nb, LNB, 1024);
    gemm32<1><<<1024, 512, 0, stream>>>(LNB, WT_FF2W1, ff2_b1, nullptr, 0.f, HID, nullptr, nullptr, M, 4096, 1024, 32);
    gemm32<3><<<256, 512, 0, stream>>>(HID, WT_FF2W2, ff2_b2, XR, 0.5f, XR, nullptr, nullptr, M, 1024, 4096, 8);

    // --- final LN -> d_out (fp32) ---
    ln_kernel<1><<<M, 256, 0, stream>>>(XR, fin_g, fin_b, d_out, 1024);
}